// Round 6
// baseline (872.725 us; speedup 1.0000x reference)
//
#include <hip/hip_runtime.h>

typedef unsigned int u32;
typedef unsigned short ushort_t;

// problem dims
#define NTOP 50
#define NT_T 50
#define NRHO 300
#define NVOC 20000
#define NTH 800
#define NEH 200
#define NSRC 10
#define NBAT 256

// ws offsets (float units), all 8-float (32B) aligned
#define OFF_SCAL     0          // 5 accumulators
#define OFF_MAPPED   16         // 500*200 fp32 (atomic)
#define OFF_HPRE     100016     // 256*800 fp32 (atomic)
#define OFF_H2       304816     // 256*800 fp32 (atomic)
#define OFF_Z        509616     // 2500 fp32 (atomic row-sums of E)
#define OFF_DOCCNT   512120     // 50 ints
#define OFF_DOCLIST  512176     // 50*256 ints
#define MEMSET_BYTES ((size_t)524976 * 4)
#define OFF_XW       524976     // 500*800 fp32
#define OFF_BIAS2    924976     // 800
#define OFF_ETAS     925776     // 10*50*50
#define OFF_WCOEF    950776     // 256*50
#define OFF_W1E      963576     // 800*50 compact W1[:,V:]
#define OFF_WHH_H    1003576    // 80000 u32 (f16 pairs) rows of 100
#define OFF_ETAWH    1083576    // 12800 u32 (f16 pairs) rows of 128 (125 used + 3 zero)
#define OFF_H1B      1096376    // bf16 [256][800]
#define OFF_MAPB     1198776    // bf16 [512][224]
#define OFF_WIHB     1256120    // bf16 [896][224]
#define OFF_W2B      1356472    // bf16 [896][800]
#define OFF_ALPHAB   1714872    // bf16 [2560][320]
#define OFF_RHOB     2124472    // bf16 [20096][320]
#define OFF_NBB      5339832    // bf16 [256][20000]
// union: {W1B, RNNB, EMWB} reused by E (LOGITH) after mapped/hpre gemms
#define OFF_W1B      7899832    // bf16 [896][20000]
#define OFF_RNNB     16859832   // bf16 [512][20000]
#define OFF_EMWB     21979832   // bf16 [256][20000]
#define OFF_LOGITH   7899832    // f16 E [2500][20000]
// total ws: 24,539,832 floats = 98.16 MB

typedef _Float16 h2v __attribute__((ext_vector_type(2)));
typedef __bf16 bf16x8 __attribute__((ext_vector_type(8)));
typedef float f32x4 __attribute__((ext_vector_type(4)));

#define REP25(M) M(0) M(1) M(2) M(3) M(4) M(5) M(6) M(7) M(8) M(9) M(10) M(11) M(12) \
                 M(13) M(14) M(15) M(16) M(17) M(18) M(19) M(20) M(21) M(22) M(23) M(24)
#define REP7(M) M(0) M(1) M(2) M(3) M(4) M(5) M(6)

__device__ inline float dot2u(u32 a, u32 b, float c){
  h2v ha = __builtin_bit_cast(h2v, a), hb = __builtin_bit_cast(h2v, b);
#if __has_builtin(__builtin_amdgcn_fdot2)
  return __builtin_amdgcn_fdot2(ha, hb, c, false);
#else
  return c + (float)ha.x*(float)hb.x + (float)ha.y*(float)hb.y;
#endif
}

__device__ inline u32 packh2(float lo, float hi){
  h2v h; h.x = (_Float16)lo; h.y = (_Float16)hi;
  return __builtin_bit_cast(u32, h);
}

__device__ inline ushort_t f2bf(float f){
  u32 u = __builtin_bit_cast(u32, f);
  u = (u + 0x7FFFu + ((u >> 16) & 1u)) >> 16;
  return (ushort_t)u;
}

__device__ inline float fast_sig(float x){ return 1.f/(1.f + __expf(-x)); }
__device__ inline float fast_tanh(float x){ float e = __expf(2.f*x); return 1.f - 2.f/(e + 1.f); }

__device__ __forceinline__ void gl2lds16(const void* g, void* l){
  __builtin_amdgcn_global_load_lds((__attribute__((address_space(1))) void*)g,
                                   (__attribute__((address_space(3))) void*)l,
                                   16, 0, 0);
}

__device__ inline void blockReduceAdd(float v, float* red, float* target){
  int tid = threadIdx.x;
  red[tid] = v; __syncthreads();
  for (int o = blockDim.x >> 1; o > 0; o >>= 1){
    if (tid < o) red[tid] += red[tid + o];
    __syncthreads();
  }
  if (tid == 0) atomicAdd(target, red[0]);
}

// ---------------- fp32 -> bf16 16-wide chunk convert (compile-time geometry) ----------------
// dst is padded [rows..][KP16*16]; rows >= MREAL zero-filled; cols >= KUSED zero-filled.
template<int LDSRC, int MREAL, int KUSED, int KP16>
__device__ inline void conv_row16(const float* __restrict__ src, ushort_t* __restrict__ dst, int i)
{
  int row = i / KP16, cc = i - row*KP16;
  int c = cc*16;
  ushort_t* d = dst + ((size_t)row*KP16 + cc)*16;
  float v[16];
  const float* sr = src + (size_t)row*LDSRC + c;
  if (row < MREAL && c + 16 <= KUSED){
    #pragma unroll
    for (int j = 0; j < 16; j++) v[j] = sr[j];
  } else {
    #pragma unroll
    for (int j = 0; j < 16; j++){
      float x = 0.f;
      if (row < MREAL && c + j < KUSED) x = sr[j];
      v[j] = x;
    }
  }
  ushort_t o[16];
  #pragma unroll
  for (int j = 0; j < 16; j++) o[j] = f2bf(v[j]);
  *(uint4*)d = *(uint4*)o;
  *(uint4*)(d + 8) = *(uint4*)(o + 8);
}

// ---------------- mega prep/convert/klalpha kernel (grid-stride, 1528 blocks) ----------------
#define P0 64     // [0,P0)      prep items 133856
#define P1 128    // [P0,P1)     alphas chunks8 102400
#define P2 288    // [P1,P2)     rho   chunks16 20096*20
#define P3 416    // [P2,P3)     nb    chunks16 256*1250
#define P4 864    // [P3,P4)     W1    chunks16 896*1250
#define P5 1120   // [P4,P5)     rnn   chunks16 512*1250
#define P6 1248   // [P5,P6)     emw   chunks16 256*1250
#define P7 1256   // [P6,P7)     wih   chunks16 896*14
#define P8 1272   // [P7,P8)     W2    chunks16 896*50
#define P9 1528   // [P8,P9)     klalpha 750000
__global__ __launch_bounds__(256) void k_mega(
    const float* __restrict__ whh,
    const float* __restrict__ muEW, const float* __restrict__ lsEW,
    const float* __restrict__ bih, const float* __restrict__ bhh,
    const float* __restrict__ wih, const float* __restrict__ emapB,
    const float* __restrict__ W1, const int* __restrict__ times,
    const float* __restrict__ muq, const float* __restrict__ lsq,
    const float* __restrict__ rho, const float* __restrict__ nb,
    const float* __restrict__ rnn, const float* __restrict__ emapW,
    const float* __restrict__ W2f, float* __restrict__ W)
{
  int b = blockIdx.x, tid = threadIdx.x;
  __shared__ float red[256];
  if (b < P0){
    u32* whhH = (u32*)(W + OFF_WHH_H);
    u32* etaWH = (u32*)(W + OFF_ETAWH);
    for (int idx = b*256 + tid; idx < 133856; idx += P0*256){
      if (idx < 80000){
        int j = idx/100; int i = idx - j*100;
        whhH[idx] = packh2(whh[j*200 + 2*i], whh[j*200 + 2*i + 1]);
      } else if (idx < 92800){
        int d = idx - 80000; int q = d >> 7; int i = d & 127;
        u32 v = 0u;
        if (i < 125){
          const float* src = (q < 50) ? (muEW + q*250) : (lsEW + (q-50)*250);
          v = packh2(src[2*i], src[2*i+1]);
        }
        etaWH[d] = v;
      } else if (idx < 93600){
        int j = idx - 92800;
        float acc = bih[j] + bhh[j];
        const float* wr = wih + (size_t)j*200;
        #pragma unroll 4
        for (int k = 0; k < 200; k++) acc += emapB[k]*wr[k];
        W[OFF_BIAS2 + j] = acc;
      } else if (idx < 133600){
        int d = idx - 93600; int j = d/50; int k = d - j*50;
        W[OFF_W1E + d] = W1[(size_t)j*20050 + 20000 + k];
      } else {
        int bb = idx - 133600; int t = times[bb];
        int* docCnt = (int*)(W + OFF_DOCCNT);
        int* docList = (int*)(W + OFF_DOCLIST);
        int pos = atomicAdd(&docCnt[t], 1);
        docList[t*256 + pos] = bb;
      }
    }
  } else if (b < P1){
    // alphas permute+pad: dst[t*50+k][r] = muq[k][t][r]; [2560][320] bf16, chunks of 8
    ushort_t* dst = (ushort_t*)(W + OFF_ALPHAB);
    for (int idx = (b-P0)*256 + tid; idx < 102400; idx += (P1-P0)*256){
      int row = idx / 40, c = (idx - row*40) << 3;
      ushort_t out[8];
      const float* src = nullptr;
      if (row < 2500){ int t = row/50, k = row - t*50; src = muq + (size_t)k*15000 + t*300; }
      #pragma unroll
      for (int j = 0; j < 8; j++){
        int r = c + j;
        float v = (src && r < 300) ? src[r] : 0.f;
        out[j] = f2bf(v);
      }
      *(uint4*)(dst + (size_t)row*320 + c) = *(uint4*)out;
    }
  } else if (b < P2){
    ushort_t* dst = (ushort_t*)(W + OFF_RHOB);
    #pragma unroll 2
    for (int i = (b-P1)*256 + tid; i < 20096*20; i += (P2-P1)*256)
      conv_row16<300, 20000, 300, 20>(rho, dst, i);
  } else if (b < P3){
    ushort_t* dst = (ushort_t*)(W + OFF_NBB);
    #pragma unroll 2
    for (int i = (b-P2)*256 + tid; i < 256*1250; i += (P3-P2)*256)
      conv_row16<20000, 256, 20000, 1250>(nb, dst, i);
  } else if (b < P4){
    ushort_t* dst = (ushort_t*)(W + OFF_W1B);
    #pragma unroll 2
    for (int i = (b-P3)*256 + tid; i < 896*1250; i += (P4-P3)*256)
      conv_row16<20050, 800, 20000, 1250>(W1, dst, i);
  } else if (b < P5){
    ushort_t* dst = (ushort_t*)(W + OFF_RNNB);
    #pragma unroll 2
    for (int i = (b-P4)*256 + tid; i < 512*1250; i += (P5-P4)*256)
      conv_row16<20000, 500, 20000, 1250>(rnn, dst, i);
  } else if (b < P6){
    ushort_t* dst = (ushort_t*)(W + OFF_EMWB);
    #pragma unroll 2
    for (int i = (b-P5)*256 + tid; i < 256*1250; i += (P6-P5)*256)
      conv_row16<20000, 200, 20000, 1250>(emapW, dst, i);
  } else if (b < P7){
    ushort_t* dst = (ushort_t*)(W + OFF_WIHB);
    #pragma unroll 2
    for (int i = (b-P6)*256 + tid; i < 896*14; i += (P7-P6)*256)
      conv_row16<200, 800, 200, 14>(wih, dst, i);
  } else if (b < P8){
    ushort_t* dst = (ushort_t*)(W + OFF_W2B);
    #pragma unroll 2
    for (int i = (b-P7)*256 + tid; i < 896*50; i += (P8-P7)*256)
      conv_row16<800, 800, 800, 50>(W2f, dst, i);
  } else {
    // kl_alpha
    const float inv_dl = 1.f/(0.005f + 1e-6f);
    const float logdl = -5.2983173665480363f;
    float local = 0.f;
    for (int idx = (b-P8)*256 + tid; idx < 750000; idx += (P9-P8)*256){
      int rem = idx % 15000; int t = rem / 300;
      float ls = lsq[idx]; float mu = muq[idx];
      if (t == 0){
        local += 0.5f*((__expf(ls) + mu*mu)/(1.f + 1e-6f) - 1.f - ls);
      } else {
        float d = mu - muq[idx - 300];
        local += 0.5f*((__expf(ls) + d*d)*inv_dl - 1.f + logdl - ls);
      }
    }
    blockReduceAdd(local, red, W + OFF_SCAL + 1);
  }
}

// ---------------- small fp32 -> bf16 convert (for mapped, after its GEMM) ----------------
__device__ inline void conv_seg(const float* __restrict__ src, int ldsrc,
                                int Mreal, int Kused,
                                ushort_t* __restrict__ dst, int Kp, int idx)
{
  int kb = Kp >> 3;
  int row = idx / kb, c = (idx - row*kb) << 3;
  ushort_t out[8];
  #pragma unroll
  for (int j = 0; j < 8; j++){
    float v = 0.f;
    int k = c + j;
    if (row < Mreal && k < Kused) v = src[(size_t)row*ldsrc + k];
    out[j] = f2bf(v);
  }
  *(uint4*)(dst + (size_t)row*Kp + c) = *(uint4*)out;
}

__global__ __launch_bounds__(256) void k_conv(const float* __restrict__ src, int ldsrc,
                                              int Mreal, int Kused,
                                              ushort_t* __restrict__ dst, int Mp, int Kp)
{
  int idx = blockIdx.x*256 + threadIdx.x;
  int kb = Kp >> 3;
  if (idx >= Mp*kb) return;
  conv_seg(src, ldsrc, Mreal, Kused, dst, Kp, idx);
}

// ---------------- bf16 MFMA NT GEMM: C[M,N] = A[M,K] . B[N,K]^T ----------------
// MODE 0: atomic f32; MODE 2: f32 store + col-bias.
// K-loop: 2-deep LDS double-buffer, issue-early/wait-late.
template<int MODE>
__global__ __launch_bounds__(256) void mfma_nt(
    const ushort_t* __restrict__ A, int lda,
    const ushort_t* __restrict__ B, int ldb,
    float* __restrict__ C, _Float16* __restrict__ Ch, int ldc,
    const float* __restrict__ nBias,
    int M, int N, int mT, int kS, int chunks)
{
  __shared__ __align__(16) ushort_t As[2][128*32];
  __shared__ __align__(16) ushort_t Bs[2][128*32];
  int bid = blockIdx.x;
  int kIdx = bid % kS; int rest = bid / kS;
  int mIdx = rest % mT; int nIdx = rest / mT;
  int tid = threadIdx.x;
  int w = tid >> 6, l = tid & 63;
  int c0 = (int)(((long long)chunks * kIdx) / kS);
  int c1 = (int)(((long long)chunks * (kIdx+1)) / kS);
  int r0 = w*32;
  const ushort_t* ga0 = A + (size_t)(mIdx*128 + r0      + (l>>2))*lda + (l&3)*8;
  const ushort_t* ga1 = A + (size_t)(mIdx*128 + r0 + 16 + (l>>2))*lda + (l&3)*8;
  const ushort_t* gb0 = B + (size_t)(nIdx*128 + r0      + (l>>2))*ldb + (l&3)*8;
  const ushort_t* gb1 = B + (size_t)(nIdx*128 + r0 + 16 + (l>>2))*ldb + (l&3)*8;
  int wr = (w >> 1)*64, wc = (w & 1)*64;
  int lr = l & 15, lq = l >> 4;
  f32x4 acc[4][4];
  #pragma unroll
  for (int i = 0; i < 4; i++)
    #pragma unroll
    for (int j = 0; j < 4; j++)
      acc[i][j] = (f32x4)0.f;

  {
    size_t ko = (size_t)c0 * 32;
    gl2lds16(ga0 + ko, As[0] + r0*32);
    gl2lds16(ga1 + ko, As[0] + r0*32 + 512);
    gl2lds16(gb0 + ko, Bs[0] + r0*32);
    gl2lds16(gb1 + ko, Bs[0] + r0*32 + 512);
  }
  asm volatile("s_waitcnt vmcnt(0)" ::: "memory");
  __builtin_amdgcn_s_barrier();

  int cur = 0;
  for (int c = c0; c < c1; c++){
    if (c + 1 < c1){
      size_t ko = (size_t)(c + 1) * 32;
      int nxt = cur ^ 1;
      gl2lds16(ga0 + ko, As[nxt] + r0*32);
      gl2lds16(ga1 + ko, As[nxt] + r0*32 + 512);
      gl2lds16(gb0 + ko, Bs[nxt] + r0*32);
      gl2lds16(gb1 + ko, Bs[nxt] + r0*32 + 512);
    }
    bf16x8 av[4], bv[4];
    #pragma unroll
    for (int i = 0; i < 4; i++)
      av[i] = *(const bf16x8*)(As[cur] + (wr + i*16 + lr)*32 + lq*8);
    #pragma unroll
    for (int j = 0; j < 4; j++)
      bv[j] = *(const bf16x8*)(Bs[cur] + (wc + j*16 + lr)*32 + lq*8);
    #pragma unroll
    for (int i = 0; i < 4; i++)
      #pragma unroll
      for (int j = 0; j < 4; j++)
        acc[i][j] = __builtin_amdgcn_mfma_f32_16x16x32_bf16(av[i], bv[j], acc[i][j], 0, 0, 0);
    asm volatile("s_waitcnt vmcnt(0)" ::: "memory");
    __builtin_amdgcn_s_barrier();
    cur ^= 1;
  }
  #pragma unroll
  for (int i = 0; i < 4; i++){
    #pragma unroll
    for (int r = 0; r < 4; r++){
      int row = mIdx*128 + wr + i*16 + lq*4 + r;
      if (row >= M) continue;
      #pragma unroll
      for (int j = 0; j < 4; j++){
        int col = nIdx*128 + wc + j*16 + lr;
        if (col >= N) continue;
        float v = acc[i][j][r];
        if (MODE == 0)      atomicAdd(&C[(size_t)row*ldc + col], v);
        else                C[(size_t)row*ldc + col] = v + nBias[col];
      }
    }
  }
}

// ---------------- FUSED: LSTM+eta (blocks 0..9) || E-GEMM exp(alpha.rho^T) (blocks 10..1579) ----
// LSTM part verbatim (512 threads). E part: each 512-thread block computes TWO tiles —
// half h = tid>>8 owns tile v = (bid-10)*2+h (3140 tiles = 1570 blocks, no tail), with its own
// LDS double-buffer As[h]/Bs[h]. All waves compute (no dead half), fixing round-5's occupancy
// collapse. Both halves run the same 10-chunk lockstep loop -> block-wide s_barrier is safe.
__global__ __launch_bounds__(512, 4) void k_fused_lstm_E(
    const float* __restrict__ xw, const u32* __restrict__ whhH, const uint4* __restrict__ etaW4,
    const float* __restrict__ muEB, const float* __restrict__ lsEB,
    float* __restrict__ etas, float* __restrict__ W,
    const ushort_t* __restrict__ A, const ushort_t* __restrict__ B,
    _Float16* __restrict__ Ch)
{
  __shared__ __align__(16) ushort_t As[2][2][128*32];  // [half][dbuf]
  __shared__ __align__(16) ushort_t Bs[2][2][128*32];
  __shared__ uint4 hp4[2][32];
  __shared__ float zbuf[800];
  __shared__ float red[512];

  if (blockIdx.x < NSRC){
    // ================= LSTM + eta recurrence =================
    int s = blockIdx.x; int tid = threadIdx.x;
    uint4 z4; z4.x = z4.y = z4.z = z4.w = 0u;
#define DECLW(i) uint4 wa##i = z4, wb##i = z4;
    REP25(DECLW)
#undef DECLW
    float ebias = 0.f;
    if (tid < 400){
      const uint4* ra = (const uint4*)(whhH + tid*100);
      const uint4* rb = (const uint4*)(whhH + (tid + 400)*100);
#define LDW(i) wa##i = ra[i]; wb##i = rb[i];
      REP25(LDW)
#undef LDW
    } else if (tid < 500){
      int q = tid - 400;
      const uint4* re = etaW4 + q*32;
#define LDA(i) wa##i = re[i];
      REP25(LDA)
#undef LDA
#define LDB(i) wb##i = re[25+i];
      REP7(LDB)
#undef LDB
      ebias = (q < 50) ? muEB[q] : lsEB[q - 50];
    }
    float creg = 0.f, muPrev = 0.f, klLocal = 0.f;
    if (tid < 64) ((uint4*)hp4)[tid] = z4;
    __syncthreads();
    const float inv_dl = 1.f/(0.005f + 1e-6f);
    const float logdl = -5.2983173665480363f;

    for (int t = 0; t < NT_T; t++){
      const uint4* hc = hp4[t & 1];
      uint4* hn = hp4[(t + 1) & 1];
      if (tid < 400){
        float a0=0.f,a1=0.f,a2=0.f,a3=0.f,b0=0.f,b1=0.f,b2=0.f,b3=0.f;
#define DOT(i) { uint4 h = hc[i]; \
        a0 = dot2u(wa##i.x, h.x, a0); a1 = dot2u(wa##i.y, h.y, a1); \
        a2 = dot2u(wa##i.z, h.z, a2); a3 = dot2u(wa##i.w, h.w, a3); \
        b0 = dot2u(wb##i.x, h.x, b0); b1 = dot2u(wb##i.y, h.y, b1); \
        b2 = dot2u(wb##i.z, h.z, b2); b3 = dot2u(wb##i.w, h.w, b3); }
        REP25(DOT)
#undef DOT
        const float* xr = xw + (size_t)(s*50 + t)*800;
        zbuf[tid]       = ((a0+a1)+(a2+a3)) + xr[tid];
        zbuf[tid + 400] = ((b0+b1)+(b2+b3)) + xr[tid + 400];
      }
      __syncthreads();  // B1: zbuf ready
      if (tid < 200){
        float zi = zbuf[tid], zf = zbuf[200+tid], zg = zbuf[400+tid], zo = zbuf[600+tid];
        float ig = fast_sig(zi);
        float fg = fast_sig(zf);
        float gg = fast_tanh(zg);
        float og = fast_sig(zo);
        creg = fg*creg + ig*gg;
        float hv = og*fast_tanh(creg);
        ((_Float16*)hn)[tid] = (_Float16)hv;
      }
      __syncthreads();  // B2: h_t ready
      if (tid >= 400 && tid < 500){
        float e0 = ebias, e1 = 0.f, e2 = 0.f, e3 = 0.f;
#define DOTE(i) { uint4 h = hn[i]; \
        e0 = dot2u(wa##i.x, h.x, e0); e1 = dot2u(wa##i.y, h.y, e1); \
        e2 = dot2u(wa##i.z, h.z, e2); e3 = dot2u(wa##i.w, h.w, e3); }
        REP25(DOTE)
#undef DOTE
#define DOTP(i) { uint4 h = hc[25+i]; \
        e0 = dot2u(wb##i.x, h.x, e0); e1 = dot2u(wb##i.y, h.y, e1); \
        e2 = dot2u(wb##i.z, h.z, e2); e3 = dot2u(wb##i.w, h.w, e3); }
        REP7(DOTP)
#undef DOTP
        float eacc = (e0+e1)+(e2+e3);
        int q = tid - 400;
        if (q < 50){
          float mu = eacc;
          etas[(size_t)(s*50 + t)*50 + q] = mu;
          if (t == 0) klLocal += 0.5f*mu*mu/(1.f + 1e-6f);
          else { float d = mu - muPrev; klLocal += 0.5f*d*d*inv_dl; }
          muPrev = mu;
          ((_Float16*)hn)[200 + q] = (_Float16)mu;
        } else {
          float ls = eacc;
          if (t == 0) klLocal += 0.5f*(__expf(ls)/(1.f + 1e-6f) - 1.f - ls);
          else {
            ls = fminf(fmaxf(ls, -10.f), 10.f);
            klLocal += 0.5f*(__expf(ls)*inv_dl - 1.f + logdl - ls);
          }
        }
      }
    }
    __syncthreads();
    blockReduceAdd(klLocal, red, W + OFF_SCAL + 2);
  } else {
    // ================= E-GEMM (MODE 3), two tiles per block =================
    int tid = threadIdx.x;
    int h = tid >> 8, t2 = tid & 255;
    int v = (blockIdx.x - NSRC)*2 + h;          // tile id in [0, 3140)
    int mIdx = v % 20; int nIdx = v / 20;
    const int M = 2500, N = 20000, ldc = 20000;
    int w = t2 >> 6, l = t2 & 63;
    int r0 = w*32;
    const ushort_t* ga0 = A + (size_t)(mIdx*128 + r0      + (l>>2))*320 + (l&3)*8;
    const ushort_t* ga1 = A + (size_t)(mIdx*128 + r0 + 16 + (l>>2))*320 + (l&3)*8;
    const ushort_t* gb0 = B + (size_t)(nIdx*128 + r0      + (l>>2))*320 + (l&3)*8;
    const ushort_t* gb1 = B + (size_t)(nIdx*128 + r0 + 16 + (l>>2))*320 + (l&3)*8;
    int wr = (w >> 1)*64, wc = (w & 1)*64;
    int lr = l & 15, lq = l >> 4;
    f32x4 acc[4][4];
    #pragma unroll
    for (int i = 0; i < 4; i++)
      #pragma unroll
      for (int j = 0; j < 4; j++)
        acc[i][j] = (f32x4)0.f;

    gl2lds16(ga0, As[h][0] + r0*32);
    gl2lds16(ga1, As[h][0] + r0*32 + 512);
    gl2lds16(gb0, Bs[h][0] + r0*32);
    gl2lds16(gb1, Bs[h][0] + r0*32 + 512);
    asm volatile("s_waitcnt vmcnt(0)" ::: "memory");
    __builtin_amdgcn_s_barrier();

    int cur = 0;
    for (int c = 0; c < 10; c++){
      if (c + 1 < 10){
        size_t ko = (size_t)(c + 1) * 32;
        int nxt = cur ^ 1;
        gl2lds16(ga0 + ko, As[h][nxt] + r0*32);
        gl2lds16(ga1 + ko, As[h][nxt] + r0*32 + 512);
        gl2lds16(gb0 + ko, Bs[h][nxt] + r0*32);
        gl2lds16(gb1 + ko, Bs[h][nxt] + r0*32 + 512);
      }
      bf16x8 av[4], bv[4];
      #pragma unroll
      for (int i = 0; i < 4; i++)
        av[i] = *(const bf16x8*)(As[h][cur] + (wr + i*16 + lr)*32 + lq*8);
      #pragma unroll
      for (int j = 0; j < 4; j++)
        bv[j] = *(const bf16x8*)(Bs[h][cur] + (wc + j*16 + lr)*32 + lq*8);
      #pragma unroll
      for (int i = 0; i < 4; i++)
        #pragma unroll
        for (int j = 0; j < 4; j++)
          acc[i][j] = __builtin_amdgcn_mfma_f32_16x16x32_bf16(av[i], bv[j], acc[i][j], 0, 0, 0);
      asm volatile("s_waitcnt vmcnt(0)" ::: "memory");
      __builtin_amdgcn_s_barrier();
      cur ^= 1;
    }
    float* Z = W + OFF_Z;
    #pragma unroll
    for (int i = 0; i < 4; i++){
      #pragma unroll
      for (int r = 0; r < 4; r++){
        int row = mIdx*128 + wr + i*16 + lq*4 + r;
        float p = 0.f;
        if (row < M){
          #pragma unroll
          for (int j = 0; j < 4; j++){
            int col = nIdx*128 + wc + j*16 + lr;
            if (col < N){
              float e = __expf(acc[i][j][r]);
              Ch[(size_t)row*ldc + col] = (_Float16)e;
              p += e;
            }
          }
        }
        p += __shfl_xor(p, 1, 16);
        p += __shfl_xor(p, 2, 16);
        p += __shfl_xor(p, 4, 16);
        p += __shfl_xor(p, 8, 16);
        if (lr == 0 && row < M) atomicAdd(&Z[row], p);
      }
    }
  }
}

// ---------------- h1 = relu(hpre + b1 + eta_std @ W1E^T) -> bf16 ----------------
__global__ __launch_bounds__(256) void k_h1(
    const float* __restrict__ hpre, const float* __restrict__ b1, const float* __restrict__ w1e,
    const float* __restrict__ etas, const int* __restrict__ times, const int* __restrict__ srcs,
    ushort_t* __restrict__ h1B)
{
  int b = blockIdx.x, tid = threadIdx.x;
  __shared__ float et[50];
  int tb = times[b], sb = srcs[b];
  if (tid < 50) et[tid] = etas[(size_t)(sb*50 + tb)*50 + tid];
  __syncthreads();
  for (int j = tid; j < 800; j += 256){
    float acc = hpre[(size_t)b*800 + j] + b1[j];
    const float* wrow = w1e + (size_t)j*50;
    #pragma unroll
    for (int k = 0; k < 50; k++) acc += et[k]*wrow[k];
    h1B[(size_t)b*800 + j] = f2bf(fmaxf(acc, 0.f));
  }
}

// ---------------- theta head (h2pre + b2, relu folded; wcoef = theta/Z) ----------------
__global__ __launch_bounds__(256) void k_thfin(
    const float* __restrict__ h2g, const float* __restrict__ b2, const float* __restrict__ etas,
    const int* __restrict__ times, const int* __restrict__ srcs,
    const float* __restrict__ muW, const float* __restrict__ muB,
    const float* __restrict__ lsW, const float* __restrict__ lsB,
    const float* __restrict__ clsW, const float* __restrict__ clsB,
    const float* __restrict__ Zrow, float* __restrict__ wcoef, float* __restrict__ W)
{
  int b = blockIdx.x, tid = threadIdx.x;
  __shared__ float h2s[800], mu[50], lsv[50], et[50], th[50], lg[10], red[64], shm[2];
  for (int j = tid; j < 800; j += 256) h2s[j] = fmaxf(h2g[(size_t)b*800 + j] + b2[j], 0.f);
  int tb = times[b], sb = srcs[b];
  if (tid < 50) et[tid] = etas[(size_t)(sb*50 + tb)*50 + tid];
  __syncthreads();
  if (tid < 100){
    int q = (tid < 50) ? tid : tid - 50;
    const float* w = (tid < 50) ? (muW + (size_t)q*800) : (lsW + (size_t)q*800);
    float acc = (tid < 50) ? muB[q] : lsB[q];
    #pragma unroll 8
    for (int j = 0; j < 800; j++) acc += h2s[j]*w[j];
    if (tid < 50) mu[q] = acc;
    else lsv[q] = fminf(fmaxf(acc, -10.f), 10.f);
  }
  __syncthreads();
  if (tid == 0){ float m = -1e30f; for (int k = 0; k < 50; k++) m = fmaxf(m, mu[k]); shm[0] = m; }
  __syncthreads();
  if (tid < 50) th[tid] = __expf(mu[tid] - shm[0]);
  __syncthreads();
  if (tid == 0){ float z = 0.f; for (int k = 0; k < 50; k++) z += th[k]; shm[1] = z; }
  __syncthreads();
  if (tid < 64) red[tid] = 0.f;
  if (tid < 50){
    float t_ = th[tid]/shm[1]; th[tid] = t_;
    wcoef[(size_t)b*50 + tid] = t_/Zrow[tb*50 + tid];
    float d = mu[tid] - et[tid];
    red[tid] = 0.5f*((__expf(lsv[tid]) + d*d)/(1.f + 1e-6f) - 1.f - lsv[tid]);
  }
  __syncthreads();
  if (tid < 10){
    float a = clsB[tid];
    #pragma unroll
    for (int k = 0; k < 50; k++) a += th[k]*clsW[tid*50 + k];
    lg[tid] = a;
  }
  __syncthreads();
  if (tid == 0){
    float m = -1e30f; for (int i = 0; i < 10; i++) m = fmaxf(m, lg[i]);
    float z = 0.f; for (int i = 0; i < 10; i++) z += __expf(lg[i] - m);
    float lse = m + __logf(z);
    atomicAdd(W + OFF_SCAL + 4, lse - lg[sb]);
    float ssum = 0.f; for (int i = 0; i < 50; i++) ssum += red[i];
    atomicAdd(W + OFF_SCAL + 3, ssum);
  }
}

// ---------------- nll: E already exponentiated ----------------
__global__ __launch_bounds__(256) void k_nll(
    const _Float16* __restrict__ E, const float* __restrict__ wcoef,
    const float* __restrict__ bows, float* __restrict__ W)
{
  int t = blockIdx.x/10, vc = blockIdx.x%10;
  int v0 = vc*2000;
  int tid = threadIdx.x;
  const int* docCnt = (const int*)(W + OFF_DOCCNT);
  const int* docList = (const int*)(W + OFF_DOCLIST);
  __shared__ float wch[64*50];
  __shared__ int ids[64];
  __shared__ float red[256];
  int nd = docCnt[t];
  float acc = 0.f;
  for (int d0 = 0; d0 < nd; d0 += 64){
    int ndc = min(64, nd - d0);
    __syncthreads();
    for (int i = tid; i < ndc*50; i += 256){
      int d = i/50, k = i - d*50;
      int bb = docList[t*256 + d0 + d];
      if (k == 0) ids[d] = bb;
      wch[i] = wcoef[(size_t)bb*50 + k];
    }
    __syncthreads();
    for (int v = v0 + tid; v < v0 + 2000; v += 256){
      float e[50];
      #pragma unroll
      for (int k = 0; k < 50; k++)
        e[k] = (float)E[(size_t)(t*50 + k)*NVOC + v];
      for (int d = 0; d < ndc; d++){
        float s = 0.f;
        #pragma unroll
        for (int k = 0; k < 50; k++) s += wch[d*50 + k]*e[k];
        acc += bows[(size_t)ids[d]*NVOC + v]*__logf(s);
      }
    }
  }
  __syncthreads();
  blockReduceAdd(acc, red, W + OFF_SCAL + 0);
}

// ---------------- finalize ----------------
__global__ void k_final(const float* __restrict__ W, const int* __restrict__ ndocs, float* __restrict__ out)
{
  if (blockIdx.x == 0 && threadIdx.x == 0){
    float coeff = (float)ndocs[0] / 256.f;
    const float* scal = W + OFF_SCAL;
    float nll  = -scal[0]*coeff;
    float kla  = scal[1];
    float kle  = scal[2];
    float klth = scal[3]*coeff;
    float pred = scal[4]*coeff;
    out[0] = nll + kla + kle + klth + pred;
    out[1] = nll; out[2] = kla; out[3] = kle; out[4] = klth; out[5] = pred;
  }
}

extern "C" void kernel_launch(void* const* d_in, const int* in_sizes, int n_in,
                              void* d_out, int out_size, void* d_ws, size_t ws_size,
                              hipStream_t stream)
{
  (void)in_sizes; (void)n_in; (void)out_size; (void)ws_size;
  const float* bows  = (const float*)d_in[1];
  const float* nb    = (const float*)d_in[2];
  const int*   times = (const int*)d_in[3];
  const int*   srcs  = (const int*)d_in[4];
  const float* rnn   = (const float*)d_in[5];
  const int*   ndocs = (const int*)d_in[6];
  const float* muq   = (const float*)d_in[7];
  const float* lsq   = (const float*)d_in[8];
  const float* rho   = (const float*)d_in[9];
  const float* W1    = (const float*)d_in[10];
  const float* b1    = (const float*)d_in[11];
  const float* W2    = (const float*)d_in[12];
  const float* b2    = (const float*)d_in[13];
  const float* muthW = (const float*)d_in[14];
  const float* muthB = (const float*)d_in[15];
  const float* lsthW = (const float*)d_in[16];
  const float* lsthB = (const float*)d_in[17];
  const float* emapW = (const float*)d_in[18];
  const float* emapB = (const float*)d_in[19];
  const float* wih   = (const float*)d_in[20];
  const float* whh   = (const float*)d_in[21];
  const float* bih   = (const float*)d_in[22];
  const float* bhh   = (const float*)d_in[23];
  const float* muEW  = (const float*)d_in[24];
  const float* muEB  = (const float*)d_in[25];
  const float* lsEW  = (const float*)d_in[26];
  const float* lsEB  = (const float*)d_in[27];
  const float* clsW  = (const float*)d_in[28];
  const float* clsB  = (const float*)d_in[29];

  float* W = (float*)d_ws;
  ushort_t* alphaB = (ushort_t*)(W + OFF_ALPHAB);
  ushort_t* rhoB   = (ushort_t*)(W + OFF_RHOB);
  ushort_t* nbB    = (ushort_t*)(W + OFF_NBB);
  ushort_t* w1B    = (ushort_t*)(W + OFF_W1B);
  ushort_t* rnnB   = (ushort_t*)(W + OFF_RNNB);
  ushort_t* emwB   = (ushort_t*)(W + OFF_EMWB);
  ushort_t* wihB   = (ushort_t*)(W + OFF_WIHB);
  ushort_t* w2B    = (ushort_t*)(W + OFF_W2B);
  ushort_t* mapB   = (ushort_t*)(W + OFF_MAPB);
  ushort_t* h1B    = (ushort_t*)(W + OFF_H1B);
  _Float16* Ehalf  = (_Float16*)(W + OFF_LOGITH);

  hipMemsetAsync(d_ws, 0, MEMSET_BYTES, stream);

  // one launch: prep + all bf16 conversions + kl_alpha (grid-stride, 1528 blocks)
  k_mega<<<1528, 256, 0, stream>>>(whh, muEW, lsEW, bih, bhh, wih, emapB, W1, times,
                                   muq, lsq, rho, nb, rnn, emapW, W2, W);

  // mapped = rnn @ eta_map_W^T  M=500 N=200 K=20000  (split-K atomic)
  mfma_nt<0><<<4*2*32, 256, 0, stream>>>(
      rnnB, 20000, emwB, 20000, W + OFF_MAPPED, nullptr, 200, nullptr,
      500, 200, 4, 32, 625);

  // hpre = nb @ W1[:, :V]^T  M=256 N=800 K=20000  (split-K atomic)
  mfma_nt<0><<<2*7*20, 256, 0, stream>>>(
      nbB, 20000, w1B, 20000, W + OFF_HPRE, nullptr, 800, nullptr,
      256, 800, 2, 20, 625);

  // mapped -> bf16 [512][224]
  k_conv<<<56, 256, 0, stream>>>(W + OFF_MAPPED, 200, 500, 200, mapB, 512, 224);

  // xw = mapped @ wih^T + bias2  M=500 N=800 K=224
  mfma_nt<2><<<4*7, 256, 0, stream>>>(
      mapB, 224, wihB, 224, W + OFF_XW, nullptr, 800, W + OFF_BIAS2,
      500, 800, 4, 1, 7);

  // FUSED: blocks 0..9 LSTM (reads xw), blocks 10..1579 E-GEMM 2 tiles/block (overwrites
  // union region; safe: mapped & hpre GEMMs already consumed rnnB/emwB/w1B)
  k_fused_lstm_E<<<NSRC + 1570, 512, 0, stream>>>(
      W + OFF_XW, (const u32*)(W + OFF_WHH_H), (const uint4*)(W + OFF_ETAWH),
      muEB, lsEB, W + OFF_ETAS, W, alphaB, rhoB, Ehalf);

  k_h1<<<256, 256, 0, stream>>>(W + OFF_HPRE, b1, W + OFF_W1E, W + OFF_ETAS, times, srcs, h1B);

  // h2pre = h1 @ W2^T  M=256 N=800 K=800  (split-K atomic; b2+relu folded into k_thfin)
  mfma_nt<0><<<2*7*2, 256, 0, stream>>>(
      h1B, 800, w2B, 800, W + OFF_H2, nullptr, 800, nullptr,
      256, 800, 2, 2, 25);

  k_thfin<<<256, 256, 0, stream>>>(W + OFF_H2, b2, W + OFF_ETAS, times, srcs,
                                   muthW, muthB, lsthW, lsthB, clsW, clsB,
                                   W + OFF_Z, W + OFF_WCOEF, W);

  k_nll<<<500, 256, 0, stream>>>(Ehalf, W + OFF_WCOEF, bows, W);

  k_final<<<1, 64, 0, stream>>>(W, ndocs, (float*)d_out);
}

// Round 7
// 612.495 us; speedup vs baseline: 1.4249x; 1.4249x over previous
//
#include <hip/hip_runtime.h>

typedef unsigned int u32;
typedef unsigned short ushort_t;

// problem dims
#define NTOP 50
#define NT_T 50
#define NRHO 300
#define NVOC 20000
#define NTH 800
#define NEH 200
#define NSRC 10
#define NBAT 256

// ws offsets (float units), all 8-float (32B) aligned
#define OFF_SCAL     0          // 5 accumulators
#define OFF_MAPPED   16         // 500*200 fp32 (atomic)
#define OFF_HPRE     100016     // 256*800 fp32 (atomic)
#define OFF_H2       304816     // 256*800 fp32 (atomic)
#define OFF_Z        509616     // 2500 fp32 (atomic row-sums of E)
#define OFF_DOCCNT   512120     // 50 ints
#define OFF_DOCLIST  512176     // 50*256 ints
#define MEMSET_BYTES ((size_t)524976 * 4)
#define OFF_XW       524976     // 500*800 fp32
#define OFF_BIAS2    924976     // 800
#define OFF_ETAS     925776     // 10*50*50
#define OFF_WCOEF    950776     // 256*50
#define OFF_W1E      963576     // 800*50 compact W1[:,V:]
#define OFF_WHH_H    1003576    // 80000 u32 (f16 pairs) rows of 100
#define OFF_ETAWH    1083576    // 12800 u32 (f16 pairs) rows of 128 (125 used + 3 zero)
#define OFF_H1B      1096376    // bf16 [256][800]
#define OFF_MAPB     1198776    // bf16 [512][224]
#define OFF_WIHB     1256120    // bf16 [896][224]
#define OFF_W2B      1356472    // bf16 [896][800]
#define OFF_ALPHAB   1714872    // bf16 [2560][320]
#define OFF_RHOB     2124472    // bf16 [20096][320]
#define OFF_NBB      5339832    // bf16 [256][20000]
// union: {W1B, RNNB, EMWB} reused by E (LOGITH) after mapped/hpre gemms
#define OFF_W1B      7899832    // bf16 [896][20000]
#define OFF_RNNB     16859832   // bf16 [512][20000]
#define OFF_EMWB     21979832   // bf16 [256][20000]
#define OFF_LOGITH   7899832    // f16 E [2500][20000]
// total ws: 24,539,832 floats = 98.16 MB

typedef _Float16 h2v __attribute__((ext_vector_type(2)));
typedef __bf16 bf16x8 __attribute__((ext_vector_type(8)));
typedef float f32x4 __attribute__((ext_vector_type(4)));

#define REP25(M) M(0) M(1) M(2) M(3) M(4) M(5) M(6) M(7) M(8) M(9) M(10) M(11) M(12) \
                 M(13) M(14) M(15) M(16) M(17) M(18) M(19) M(20) M(21) M(22) M(23) M(24)
#define REP7(M) M(0) M(1) M(2) M(3) M(4) M(5) M(6)

__device__ inline float dot2u(u32 a, u32 b, float c){
  h2v ha = __builtin_bit_cast(h2v, a), hb = __builtin_bit_cast(h2v, b);
#if __has_builtin(__builtin_amdgcn_fdot2)
  return __builtin_amdgcn_fdot2(ha, hb, c, false);
#else
  return c + (float)ha.x*(float)hb.x + (float)ha.y*(float)hb.y;
#endif
}

__device__ inline u32 packh2(float lo, float hi){
  h2v h; h.x = (_Float16)lo; h.y = (_Float16)hi;
  return __builtin_bit_cast(u32, h);
}

__device__ inline ushort_t f2bf(float f){
  u32 u = __builtin_bit_cast(u32, f);
  u = (u + 0x7FFFu + ((u >> 16) & 1u)) >> 16;
  return (ushort_t)u;
}

__device__ inline float fast_sig(float x){ return 1.f/(1.f + __expf(-x)); }
__device__ inline float fast_tanh(float x){ float e = __expf(2.f*x); return 1.f - 2.f/(e + 1.f); }

__device__ __forceinline__ void gl2lds16(const void* g, void* l){
  __builtin_amdgcn_global_load_lds((__attribute__((address_space(1))) void*)g,
                                   (__attribute__((address_space(3))) void*)l,
                                   16, 0, 0);
}

__device__ inline void blockReduceAdd(float v, float* red, float* target){
  int tid = threadIdx.x;
  red[tid] = v; __syncthreads();
  for (int o = blockDim.x >> 1; o > 0; o >>= 1){
    if (tid < o) red[tid] += red[tid + o];
    __syncthreads();
  }
  if (tid == 0) atomicAdd(target, red[0]);
}

// ---------------- fp32 -> bf16 16-wide chunk convert (compile-time geometry) ----------------
// dst is padded [rows..][KP16*16]; rows >= MREAL zero-filled; cols >= KUSED zero-filled.
template<int LDSRC, int MREAL, int KUSED, int KP16>
__device__ inline void conv_row16(const float* __restrict__ src, ushort_t* __restrict__ dst, int i)
{
  int row = i / KP16, cc = i - row*KP16;
  int c = cc*16;
  ushort_t* d = dst + ((size_t)row*KP16 + cc)*16;
  float v[16];
  const float* sr = src + (size_t)row*LDSRC + c;
  if (row < MREAL && c + 16 <= KUSED){
    #pragma unroll
    for (int j = 0; j < 16; j++) v[j] = sr[j];
  } else {
    #pragma unroll
    for (int j = 0; j < 16; j++){
      float x = 0.f;
      if (row < MREAL && c + j < KUSED) x = sr[j];
      v[j] = x;
    }
  }
  ushort_t o[16];
  #pragma unroll
  for (int j = 0; j < 16; j++) o[j] = f2bf(v[j]);
  *(uint4*)d = *(uint4*)o;
  *(uint4*)(d + 8) = *(uint4*)(o + 8);
}

// ---------------- mega prep/convert/klalpha kernel (grid-stride, 1528 blocks) ----------------
#define P0 64     // [0,P0)      prep items 133856
#define P1 128    // [P0,P1)     alphas chunks8 102400
#define P2 288    // [P1,P2)     rho   chunks16 20096*20
#define P3 416    // [P2,P3)     nb    chunks16 256*1250
#define P4 864    // [P3,P4)     W1    chunks16 896*1250
#define P5 1120   // [P4,P5)     rnn   chunks16 512*1250
#define P6 1248   // [P5,P6)     emw   chunks16 256*1250
#define P7 1256   // [P6,P7)     wih   chunks16 896*14
#define P8 1272   // [P7,P8)     W2    chunks16 896*50
#define P9 1528   // [P8,P9)     klalpha 750000
__global__ __launch_bounds__(256) void k_mega(
    const float* __restrict__ whh,
    const float* __restrict__ muEW, const float* __restrict__ lsEW,
    const float* __restrict__ bih, const float* __restrict__ bhh,
    const float* __restrict__ wih, const float* __restrict__ emapB,
    const float* __restrict__ W1, const int* __restrict__ times,
    const float* __restrict__ muq, const float* __restrict__ lsq,
    const float* __restrict__ rho, const float* __restrict__ nb,
    const float* __restrict__ rnn, const float* __restrict__ emapW,
    const float* __restrict__ W2f, float* __restrict__ W)
{
  int b = blockIdx.x, tid = threadIdx.x;
  __shared__ float red[256];
  if (b < P0){
    u32* whhH = (u32*)(W + OFF_WHH_H);
    u32* etaWH = (u32*)(W + OFF_ETAWH);
    for (int idx = b*256 + tid; idx < 133856; idx += P0*256){
      if (idx < 80000){
        int j = idx/100; int i = idx - j*100;
        whhH[idx] = packh2(whh[j*200 + 2*i], whh[j*200 + 2*i + 1]);
      } else if (idx < 92800){
        int d = idx - 80000; int q = d >> 7; int i = d & 127;
        u32 v = 0u;
        if (i < 125){
          const float* src = (q < 50) ? (muEW + q*250) : (lsEW + (q-50)*250);
          v = packh2(src[2*i], src[2*i+1]);
        }
        etaWH[d] = v;
      } else if (idx < 93600){
        int j = idx - 92800;
        float acc = bih[j] + bhh[j];
        const float* wr = wih + (size_t)j*200;
        #pragma unroll 4
        for (int k = 0; k < 200; k++) acc += emapB[k]*wr[k];
        W[OFF_BIAS2 + j] = acc;
      } else if (idx < 133600){
        int d = idx - 93600; int j = d/50; int k = d - j*50;
        W[OFF_W1E + d] = W1[(size_t)j*20050 + 20000 + k];
      } else {
        int bb = idx - 133600; int t = times[bb];
        int* docCnt = (int*)(W + OFF_DOCCNT);
        int* docList = (int*)(W + OFF_DOCLIST);
        int pos = atomicAdd(&docCnt[t], 1);
        docList[t*256 + pos] = bb;
      }
    }
  } else if (b < P1){
    // alphas permute+pad: dst[t*50+k][r] = muq[k][t][r]; [2560][320] bf16, chunks of 8
    ushort_t* dst = (ushort_t*)(W + OFF_ALPHAB);
    for (int idx = (b-P0)*256 + tid; idx < 102400; idx += (P1-P0)*256){
      int row = idx / 40, c = (idx - row*40) << 3;
      ushort_t out[8];
      const float* src = nullptr;
      if (row < 2500){ int t = row/50, k = row - t*50; src = muq + (size_t)k*15000 + t*300; }
      #pragma unroll
      for (int j = 0; j < 8; j++){
        int r = c + j;
        float v = (src && r < 300) ? src[r] : 0.f;
        out[j] = f2bf(v);
      }
      *(uint4*)(dst + (size_t)row*320 + c) = *(uint4*)out;
    }
  } else if (b < P2){
    ushort_t* dst = (ushort_t*)(W + OFF_RHOB);
    #pragma unroll 2
    for (int i = (b-P1)*256 + tid; i < 20096*20; i += (P2-P1)*256)
      conv_row16<300, 20000, 300, 20>(rho, dst, i);
  } else if (b < P3){
    ushort_t* dst = (ushort_t*)(W + OFF_NBB);
    #pragma unroll 2
    for (int i = (b-P2)*256 + tid; i < 256*1250; i += (P3-P2)*256)
      conv_row16<20000, 256, 20000, 1250>(nb, dst, i);
  } else if (b < P4){
    ushort_t* dst = (ushort_t*)(W + OFF_W1B);
    #pragma unroll 2
    for (int i = (b-P3)*256 + tid; i < 896*1250; i += (P4-P3)*256)
      conv_row16<20050, 800, 20000, 1250>(W1, dst, i);
  } else if (b < P5){
    ushort_t* dst = (ushort_t*)(W + OFF_RNNB);
    #pragma unroll 2
    for (int i = (b-P4)*256 + tid; i < 512*1250; i += (P5-P4)*256)
      conv_row16<20000, 500, 20000, 1250>(rnn, dst, i);
  } else if (b < P6){
    ushort_t* dst = (ushort_t*)(W + OFF_EMWB);
    #pragma unroll 2
    for (int i = (b-P5)*256 + tid; i < 256*1250; i += (P6-P5)*256)
      conv_row16<20000, 200, 20000, 1250>(emapW, dst, i);
  } else if (b < P7){
    ushort_t* dst = (ushort_t*)(W + OFF_WIHB);
    #pragma unroll 2
    for (int i = (b-P6)*256 + tid; i < 896*14; i += (P7-P6)*256)
      conv_row16<200, 800, 200, 14>(wih, dst, i);
  } else if (b < P8){
    ushort_t* dst = (ushort_t*)(W + OFF_W2B);
    #pragma unroll 2
    for (int i = (b-P7)*256 + tid; i < 896*50; i += (P8-P7)*256)
      conv_row16<800, 800, 800, 50>(W2f, dst, i);
  } else {
    // kl_alpha
    const float inv_dl = 1.f/(0.005f + 1e-6f);
    const float logdl = -5.2983173665480363f;
    float local = 0.f;
    for (int idx = (b-P8)*256 + tid; idx < 750000; idx += (P9-P8)*256){
      int rem = idx % 15000; int t = rem / 300;
      float ls = lsq[idx]; float mu = muq[idx];
      if (t == 0){
        local += 0.5f*((__expf(ls) + mu*mu)/(1.f + 1e-6f) - 1.f - ls);
      } else {
        float d = mu - muq[idx - 300];
        local += 0.5f*((__expf(ls) + d*d)*inv_dl - 1.f + logdl - ls);
      }
    }
    blockReduceAdd(local, red, W + OFF_SCAL + 1);
  }
}

// ---------------- small fp32 -> bf16 convert (for mapped, after its GEMM) ----------------
__device__ inline void conv_seg(const float* __restrict__ src, int ldsrc,
                                int Mreal, int Kused,
                                ushort_t* __restrict__ dst, int Kp, int idx)
{
  int kb = Kp >> 3;
  int row = idx / kb, c = (idx - row*kb) << 3;
  ushort_t out[8];
  #pragma unroll
  for (int j = 0; j < 8; j++){
    float v = 0.f;
    int k = c + j;
    if (row < Mreal && k < Kused) v = src[(size_t)row*ldsrc + k];
    out[j] = f2bf(v);
  }
  *(uint4*)(dst + (size_t)row*Kp + c) = *(uint4*)out;
}

__global__ __launch_bounds__(256) void k_conv(const float* __restrict__ src, int ldsrc,
                                              int Mreal, int Kused,
                                              ushort_t* __restrict__ dst, int Mp, int Kp)
{
  int idx = blockIdx.x*256 + threadIdx.x;
  int kb = Kp >> 3;
  if (idx >= Mp*kb) return;
  conv_seg(src, ldsrc, Mreal, Kused, dst, Kp, idx);
}

// ---------------- bf16 MFMA NT GEMM: C[M,N] = A[M,K] . B[N,K]^T ----------------
// MODE 0: atomic f32; MODE 2: f32 store + col-bias.
// K-loop: 2-deep LDS double-buffer, issue-early/wait-late.
template<int MODE>
__global__ __launch_bounds__(256) void mfma_nt(
    const ushort_t* __restrict__ A, int lda,
    const ushort_t* __restrict__ B, int ldb,
    float* __restrict__ C, _Float16* __restrict__ Ch, int ldc,
    const float* __restrict__ nBias,
    int M, int N, int mT, int kS, int chunks)
{
  __shared__ __align__(16) ushort_t As[2][128*32];
  __shared__ __align__(16) ushort_t Bs[2][128*32];
  int bid = blockIdx.x;
  int kIdx = bid % kS; int rest = bid / kS;
  int mIdx = rest % mT; int nIdx = rest / mT;
  int tid = threadIdx.x;
  int w = tid >> 6, l = tid & 63;
  int c0 = (int)(((long long)chunks * kIdx) / kS);
  int c1 = (int)(((long long)chunks * (kIdx+1)) / kS);
  int r0 = w*32;
  const ushort_t* ga0 = A + (size_t)(mIdx*128 + r0      + (l>>2))*lda + (l&3)*8;
  const ushort_t* ga1 = A + (size_t)(mIdx*128 + r0 + 16 + (l>>2))*lda + (l&3)*8;
  const ushort_t* gb0 = B + (size_t)(nIdx*128 + r0      + (l>>2))*ldb + (l&3)*8;
  const ushort_t* gb1 = B + (size_t)(nIdx*128 + r0 + 16 + (l>>2))*ldb + (l&3)*8;
  int wr = (w >> 1)*64, wc = (w & 1)*64;
  int lr = l & 15, lq = l >> 4;
  f32x4 acc[4][4];
  #pragma unroll
  for (int i = 0; i < 4; i++)
    #pragma unroll
    for (int j = 0; j < 4; j++)
      acc[i][j] = (f32x4)0.f;

  {
    size_t ko = (size_t)c0 * 32;
    gl2lds16(ga0 + ko, As[0] + r0*32);
    gl2lds16(ga1 + ko, As[0] + r0*32 + 512);
    gl2lds16(gb0 + ko, Bs[0] + r0*32);
    gl2lds16(gb1 + ko, Bs[0] + r0*32 + 512);
  }
  asm volatile("s_waitcnt vmcnt(0)" ::: "memory");
  __builtin_amdgcn_s_barrier();

  int cur = 0;
  for (int c = c0; c < c1; c++){
    if (c + 1 < c1){
      size_t ko = (size_t)(c + 1) * 32;
      int nxt = cur ^ 1;
      gl2lds16(ga0 + ko, As[nxt] + r0*32);
      gl2lds16(ga1 + ko, As[nxt] + r0*32 + 512);
      gl2lds16(gb0 + ko, Bs[nxt] + r0*32);
      gl2lds16(gb1 + ko, Bs[nxt] + r0*32 + 512);
    }
    bf16x8 av[4], bv[4];
    #pragma unroll
    for (int i = 0; i < 4; i++)
      av[i] = *(const bf16x8*)(As[cur] + (wr + i*16 + lr)*32 + lq*8);
    #pragma unroll
    for (int j = 0; j < 4; j++)
      bv[j] = *(const bf16x8*)(Bs[cur] + (wc + j*16 + lr)*32 + lq*8);
    #pragma unroll
    for (int i = 0; i < 4; i++)
      #pragma unroll
      for (int j = 0; j < 4; j++)
        acc[i][j] = __builtin_amdgcn_mfma_f32_16x16x32_bf16(av[i], bv[j], acc[i][j], 0, 0, 0);
    asm volatile("s_waitcnt vmcnt(0)" ::: "memory");
    __builtin_amdgcn_s_barrier();
    cur ^= 1;
  }
  #pragma unroll
  for (int i = 0; i < 4; i++){
    #pragma unroll
    for (int r = 0; r < 4; r++){
      int row = mIdx*128 + wr + i*16 + lq*4 + r;
      if (row >= M) continue;
      #pragma unroll
      for (int j = 0; j < 4; j++){
        int col = nIdx*128 + wc + j*16 + lr;
        if (col >= N) continue;
        float v = acc[i][j][r];
        if (MODE == 0)      atomicAdd(&C[(size_t)row*ldc + col], v);
        else                C[(size_t)row*ldc + col] = v + nBias[col];
      }
    }
  }
}

// ---------------- FUSED: LSTM+eta (blocks 0..9) || E-GEMM exp(alpha.rho^T) (blocks 10..1579) ----
// LSTM part verbatim (512 threads). E part: each 512-thread block computes TWO tiles —
// half h = tid>>8 owns tile v = (bid-10)*2+h (3140 tiles = 1570 blocks, no tail), with its own
// LDS double-buffer As[h]/Bs[h]. All waves compute.
// __launch_bounds__(512, 2): min-waves=2/EU caps VGPR at 256 — round 6's (512,4) capped at 128
// and collapsed the allocator to 64 VGPR + massive scratch spills (both LSTM weights and GEMM
// accumulators), 390 us. With cap 256 the same branches compiled to 120 VGPR in round 5
// -> 16 waves/CU (VGPR) x 2 blocks/CU (70.5KB LDS), all waves computing.
__global__ __launch_bounds__(512, 2) void k_fused_lstm_E(
    const float* __restrict__ xw, const u32* __restrict__ whhH, const uint4* __restrict__ etaW4,
    const float* __restrict__ muEB, const float* __restrict__ lsEB,
    float* __restrict__ etas, float* __restrict__ W,
    const ushort_t* __restrict__ A, const ushort_t* __restrict__ B,
    _Float16* __restrict__ Ch)
{
  __shared__ __align__(16) ushort_t As[2][2][128*32];  // [half][dbuf]
  __shared__ __align__(16) ushort_t Bs[2][2][128*32];
  __shared__ uint4 hp4[2][32];
  __shared__ float zbuf[800];
  __shared__ float red[512];

  if (blockIdx.x < NSRC){
    // ================= LSTM + eta recurrence =================
    int s = blockIdx.x; int tid = threadIdx.x;
    uint4 z4; z4.x = z4.y = z4.z = z4.w = 0u;
#define DECLW(i) uint4 wa##i = z4, wb##i = z4;
    REP25(DECLW)
#undef DECLW
    float ebias = 0.f;
    if (tid < 400){
      const uint4* ra = (const uint4*)(whhH + tid*100);
      const uint4* rb = (const uint4*)(whhH + (tid + 400)*100);
#define LDW(i) wa##i = ra[i]; wb##i = rb[i];
      REP25(LDW)
#undef LDW
    } else if (tid < 500){
      int q = tid - 400;
      const uint4* re = etaW4 + q*32;
#define LDA(i) wa##i = re[i];
      REP25(LDA)
#undef LDA
#define LDB(i) wb##i = re[25+i];
      REP7(LDB)
#undef LDB
      ebias = (q < 50) ? muEB[q] : lsEB[q - 50];
    }
    float creg = 0.f, muPrev = 0.f, klLocal = 0.f;
    if (tid < 64) ((uint4*)hp4)[tid] = z4;
    __syncthreads();
    const float inv_dl = 1.f/(0.005f + 1e-6f);
    const float logdl = -5.2983173665480363f;

    for (int t = 0; t < NT_T; t++){
      const uint4* hc = hp4[t & 1];
      uint4* hn = hp4[(t + 1) & 1];
      if (tid < 400){
        float a0=0.f,a1=0.f,a2=0.f,a3=0.f,b0=0.f,b1=0.f,b2=0.f,b3=0.f;
#define DOT(i) { uint4 h = hc[i]; \
        a0 = dot2u(wa##i.x, h.x, a0); a1 = dot2u(wa##i.y, h.y, a1); \
        a2 = dot2u(wa##i.z, h.z, a2); a3 = dot2u(wa##i.w, h.w, a3); \
        b0 = dot2u(wb##i.x, h.x, b0); b1 = dot2u(wb##i.y, h.y, b1); \
        b2 = dot2u(wb##i.z, h.z, b2); b3 = dot2u(wb##i.w, h.w, b3); }
        REP25(DOT)
#undef DOT
        const float* xr = xw + (size_t)(s*50 + t)*800;
        zbuf[tid]       = ((a0+a1)+(a2+a3)) + xr[tid];
        zbuf[tid + 400] = ((b0+b1)+(b2+b3)) + xr[tid + 400];
      }
      __syncthreads();  // B1: zbuf ready
      if (tid < 200){
        float zi = zbuf[tid], zf = zbuf[200+tid], zg = zbuf[400+tid], zo = zbuf[600+tid];
        float ig = fast_sig(zi);
        float fg = fast_sig(zf);
        float gg = fast_tanh(zg);
        float og = fast_sig(zo);
        creg = fg*creg + ig*gg;
        float hv = og*fast_tanh(creg);
        ((_Float16*)hn)[tid] = (_Float16)hv;
      }
      __syncthreads();  // B2: h_t ready
      if (tid >= 400 && tid < 500){
        float e0 = ebias, e1 = 0.f, e2 = 0.f, e3 = 0.f;
#define DOTE(i) { uint4 h = hn[i]; \
        e0 = dot2u(wa##i.x, h.x, e0); e1 = dot2u(wa##i.y, h.y, e1); \
        e2 = dot2u(wa##i.z, h.z, e2); e3 = dot2u(wa##i.w, h.w, e3); }
        REP25(DOTE)
#undef DOTE
#define DOTP(i) { uint4 h = hc[25+i]; \
        e0 = dot2u(wb##i.x, h.x, e0); e1 = dot2u(wb##i.y, h.y, e1); \
        e2 = dot2u(wb##i.z, h.z, e2); e3 = dot2u(wb##i.w, h.w, e3); }
        REP7(DOTP)
#undef DOTP
        float eacc = (e0+e1)+(e2+e3);
        int q = tid - 400;
        if (q < 50){
          float mu = eacc;
          etas[(size_t)(s*50 + t)*50 + q] = mu;
          if (t == 0) klLocal += 0.5f*mu*mu/(1.f + 1e-6f);
          else { float d = mu - muPrev; klLocal += 0.5f*d*d*inv_dl; }
          muPrev = mu;
          ((_Float16*)hn)[200 + q] = (_Float16)mu;
        } else {
          float ls = eacc;
          if (t == 0) klLocal += 0.5f*(__expf(ls)/(1.f + 1e-6f) - 1.f - ls);
          else {
            ls = fminf(fmaxf(ls, -10.f), 10.f);
            klLocal += 0.5f*(__expf(ls)*inv_dl - 1.f + logdl - ls);
          }
        }
      }
    }
    __syncthreads();
    blockReduceAdd(klLocal, red, W + OFF_SCAL + 2);
  } else {
    // ================= E-GEMM (MODE 3), two tiles per block =================
    int tid = threadIdx.x;
    int h = tid >> 8, t2 = tid & 255;
    int v = (blockIdx.x - NSRC)*2 + h;          // tile id in [0, 3140)
    int mIdx = v % 20; int nIdx = v / 20;
    const int M = 2500, N = 20000, ldc = 20000;
    int w = t2 >> 6, l = t2 & 63;
    int r0 = w*32;
    const ushort_t* ga0 = A + (size_t)(mIdx*128 + r0      + (l>>2))*320 + (l&3)*8;
    const ushort_t* ga1 = A + (size_t)(mIdx*128 + r0 + 16 + (l>>2))*320 + (l&3)*8;
    const ushort_t* gb0 = B + (size_t)(nIdx*128 + r0      + (l>>2))*320 + (l&3)*8;
    const ushort_t* gb1 = B + (size_t)(nIdx*128 + r0 + 16 + (l>>2))*320 + (l&3)*8;
    int wr = (w >> 1)*64, wc = (w & 1)*64;
    int lr = l & 15, lq = l >> 4;
    f32x4 acc[4][4];
    #pragma unroll
    for (int i = 0; i < 4; i++)
      #pragma unroll
      for (int j = 0; j < 4; j++)
        acc[i][j] = (f32x4)0.f;

    gl2lds16(ga0, As[h][0] + r0*32);
    gl2lds16(ga1, As[h][0] + r0*32 + 512);
    gl2lds16(gb0, Bs[h][0] + r0*32);
    gl2lds16(gb1, Bs[h][0] + r0*32 + 512);
    asm volatile("s_waitcnt vmcnt(0)" ::: "memory");
    __builtin_amdgcn_s_barrier();

    int cur = 0;
    for (int c = 0; c < 10; c++){
      if (c + 1 < 10){
        size_t ko = (size_t)(c + 1) * 32;
        int nxt = cur ^ 1;
        gl2lds16(ga0 + ko, As[h][nxt] + r0*32);
        gl2lds16(ga1 + ko, As[h][nxt] + r0*32 + 512);
        gl2lds16(gb0 + ko, Bs[h][nxt] + r0*32);
        gl2lds16(gb1 + ko, Bs[h][nxt] + r0*32 + 512);
      }
      bf16x8 av[4], bv[4];
      #pragma unroll
      for (int i = 0; i < 4; i++)
        av[i] = *(const bf16x8*)(As[h][cur] + (wr + i*16 + lr)*32 + lq*8);
      #pragma unroll
      for (int j = 0; j < 4; j++)
        bv[j] = *(const bf16x8*)(Bs[h][cur] + (wc + j*16 + lr)*32 + lq*8);
      #pragma unroll
      for (int i = 0; i < 4; i++)
        #pragma unroll
        for (int j = 0; j < 4; j++)
          acc[i][j] = __builtin_amdgcn_mfma_f32_16x16x32_bf16(av[i], bv[j], acc[i][j], 0, 0, 0);
      asm volatile("s_waitcnt vmcnt(0)" ::: "memory");
      __builtin_amdgcn_s_barrier();
      cur ^= 1;
    }
    float* Z = W + OFF_Z;
    #pragma unroll
    for (int i = 0; i < 4; i++){
      #pragma unroll
      for (int r = 0; r < 4; r++){
        int row = mIdx*128 + wr + i*16 + lq*4 + r;
        float p = 0.f;
        if (row < M){
          #pragma unroll
          for (int j = 0; j < 4; j++){
            int col = nIdx*128 + wc + j*16 + lr;
            if (col < N){
              float e = __expf(acc[i][j][r]);
              Ch[(size_t)row*ldc + col] = (_Float16)e;
              p += e;
            }
          }
        }
        p += __shfl_xor(p, 1, 16);
        p += __shfl_xor(p, 2, 16);
        p += __shfl_xor(p, 4, 16);
        p += __shfl_xor(p, 8, 16);
        if (lr == 0 && row < M) atomicAdd(&Z[row], p);
      }
    }
  }
}

// ---------------- h1 = relu(hpre + b1 + eta_std @ W1E^T) -> bf16 ----------------
__global__ __launch_bounds__(256) void k_h1(
    const float* __restrict__ hpre, const float* __restrict__ b1, const float* __restrict__ w1e,
    const float* __restrict__ etas, const int* __restrict__ times, const int* __restrict__ srcs,
    ushort_t* __restrict__ h1B)
{
  int b = blockIdx.x, tid = threadIdx.x;
  __shared__ float et[50];
  int tb = times[b], sb = srcs[b];
  if (tid < 50) et[tid] = etas[(size_t)(sb*50 + tb)*50 + tid];
  __syncthreads();
  for (int j = tid; j < 800; j += 256){
    float acc = hpre[(size_t)b*800 + j] + b1[j];
    const float* wrow = w1e + (size_t)j*50;
    #pragma unroll
    for (int k = 0; k < 50; k++) acc += et[k]*wrow[k];
    h1B[(size_t)b*800 + j] = f2bf(fmaxf(acc, 0.f));
  }
}

// ---------------- theta head (h2pre + b2, relu folded; wcoef = theta/Z) ----------------
__global__ __launch_bounds__(256) void k_thfin(
    const float* __restrict__ h2g, const float* __restrict__ b2, const float* __restrict__ etas,
    const int* __restrict__ times, const int* __restrict__ srcs,
    const float* __restrict__ muW, const float* __restrict__ muB,
    const float* __restrict__ lsW, const float* __restrict__ lsB,
    const float* __restrict__ clsW, const float* __restrict__ clsB,
    const float* __restrict__ Zrow, float* __restrict__ wcoef, float* __restrict__ W)
{
  int b = blockIdx.x, tid = threadIdx.x;
  __shared__ float h2s[800], mu[50], lsv[50], et[50], th[50], lg[10], red[64], shm[2];
  for (int j = tid; j < 800; j += 256) h2s[j] = fmaxf(h2g[(size_t)b*800 + j] + b2[j], 0.f);
  int tb = times[b], sb = srcs[b];
  if (tid < 50) et[tid] = etas[(size_t)(sb*50 + tb)*50 + tid];
  __syncthreads();
  if (tid < 100){
    int q = (tid < 50) ? tid : tid - 50;
    const float* w = (tid < 50) ? (muW + (size_t)q*800) : (lsW + (size_t)q*800);
    float acc = (tid < 50) ? muB[q] : lsB[q];
    #pragma unroll 8
    for (int j = 0; j < 800; j++) acc += h2s[j]*w[j];
    if (tid < 50) mu[q] = acc;
    else lsv[q] = fminf(fmaxf(acc, -10.f), 10.f);
  }
  __syncthreads();
  if (tid == 0){ float m = -1e30f; for (int k = 0; k < 50; k++) m = fmaxf(m, mu[k]); shm[0] = m; }
  __syncthreads();
  if (tid < 50) th[tid] = __expf(mu[tid] - shm[0]);
  __syncthreads();
  if (tid == 0){ float z = 0.f; for (int k = 0; k < 50; k++) z += th[k]; shm[1] = z; }
  __syncthreads();
  if (tid < 64) red[tid] = 0.f;
  if (tid < 50){
    float t_ = th[tid]/shm[1]; th[tid] = t_;
    wcoef[(size_t)b*50 + tid] = t_/Zrow[tb*50 + tid];
    float d = mu[tid] - et[tid];
    red[tid] = 0.5f*((__expf(lsv[tid]) + d*d)/(1.f + 1e-6f) - 1.f - lsv[tid]);
  }
  __syncthreads();
  if (tid < 10){
    float a = clsB[tid];
    #pragma unroll
    for (int k = 0; k < 50; k++) a += th[k]*clsW[tid*50 + k];
    lg[tid] = a;
  }
  __syncthreads();
  if (tid == 0){
    float m = -1e30f; for (int i = 0; i < 10; i++) m = fmaxf(m, lg[i]);
    float z = 0.f; for (int i = 0; i < 10; i++) z += __expf(lg[i] - m);
    float lse = m + __logf(z);
    atomicAdd(W + OFF_SCAL + 4, lse - lg[sb]);
    float ssum = 0.f; for (int i = 0; i < 50; i++) ssum += red[i];
    atomicAdd(W + OFF_SCAL + 3, ssum);
  }
}

// ---------------- nll: E already exponentiated ----------------
__global__ __launch_bounds__(256) void k_nll(
    const _Float16* __restrict__ E, const float* __restrict__ wcoef,
    const float* __restrict__ bows, float* __restrict__ W)
{
  int t = blockIdx.x/10, vc = blockIdx.x%10;
  int v0 = vc*2000;
  int tid = threadIdx.x;
  const int* docCnt = (const int*)(W + OFF_DOCCNT);
  const int* docList = (const int*)(W + OFF_DOCLIST);
  __shared__ float wch[64*50];
  __shared__ int ids[64];
  __shared__ float red[256];
  int nd = docCnt[t];
  float acc = 0.f;
  for (int d0 = 0; d0 < nd; d0 += 64){
    int ndc = min(64, nd - d0);
    __syncthreads();
    for (int i = tid; i < ndc*50; i += 256){
      int d = i/50, k = i - d*50;
      int bb = docList[t*256 + d0 + d];
      if (k == 0) ids[d] = bb;
      wch[i] = wcoef[(size_t)bb*50 + k];
    }
    __syncthreads();
    for (int v = v0 + tid; v < v0 + 2000; v += 256){
      float e[50];
      #pragma unroll
      for (int k = 0; k < 50; k++)
        e[k] = (float)E[(size_t)(t*50 + k)*NVOC + v];
      for (int d = 0; d < ndc; d++){
        float s = 0.f;
        #pragma unroll
        for (int k = 0; k < 50; k++) s += wch[d*50 + k]*e[k];
        acc += bows[(size_t)ids[d]*NVOC + v]*__logf(s);
      }
    }
  }
  __syncthreads();
  blockReduceAdd(acc, red, W + OFF_SCAL + 0);
}

// ---------------- finalize ----------------
__global__ void k_final(const float* __restrict__ W, const int* __restrict__ ndocs, float* __restrict__ out)
{
  if (blockIdx.x == 0 && threadIdx.x == 0){
    float coeff = (float)ndocs[0] / 256.f;
    const float* scal = W + OFF_SCAL;
    float nll  = -scal[0]*coeff;
    float kla  = scal[1];
    float kle  = scal[2];
    float klth = scal[3]*coeff;
    float pred = scal[4]*coeff;
    out[0] = nll + kla + kle + klth + pred;
    out[1] = nll; out[2] = kla; out[3] = kle; out[4] = klth; out[5] = pred;
  }
}

extern "C" void kernel_launch(void* const* d_in, const int* in_sizes, int n_in,
                              void* d_out, int out_size, void* d_ws, size_t ws_size,
                              hipStream_t stream)
{
  (void)in_sizes; (void)n_in; (void)out_size; (void)ws_size;
  const float* bows  = (const float*)d_in[1];
  const float* nb    = (const float*)d_in[2];
  const int*   times = (const int*)d_in[3];
  const int*   srcs  = (const int*)d_in[4];
  const float* rnn   = (const float*)d_in[5];
  const int*   ndocs = (const int*)d_in[6];
  const float* muq   = (const float*)d_in[7];
  const float* lsq   = (const float*)d_in[8];
  const float* rho   = (const float*)d_in[9];
  const float* W1    = (const float*)d_in[10];
  const float* b1    = (const float*)d_in[11];
  const float* W2    = (const float*)d_in[12];
  const float* b2    = (const float*)d_in[13];
  const float* muthW = (const float*)d_in[14];
  const float* muthB = (const float*)d_in[15];
  const float* lsthW = (const float*)d_in[16];
  const float* lsthB = (const float*)d_in[17];
  const float* emapW = (const float*)d_in[18];
  const float* emapB = (const float*)d_in[19];
  const float* wih   = (const float*)d_in[20];
  const float* whh   = (const float*)d_in[21];
  const float* bih   = (const float*)d_in[22];
  const float* bhh   = (const float*)d_in[23];
  const float* muEW  = (const float*)d_in[24];
  const float* muEB  = (const float*)d_in[25];
  const float* lsEW  = (const float*)d_in[26];
  const float* lsEB  = (const float*)d_in[27];
  const float* clsW  = (const float*)d_in[28];
  const float* clsB  = (const float*)d_in[29];

  float* W = (float*)d_ws;
  ushort_t* alphaB = (ushort_t*)(W + OFF_ALPHAB);
  ushort_t* rhoB   = (ushort_t*)(W + OFF_RHOB);
  ushort_t* nbB    = (ushort_t*)(W + OFF_NBB);
  ushort_t* w1B    = (ushort_t*)(W + OFF_W1B);
  ushort_t* rnnB   = (ushort_t*)(W + OFF_RNNB);
  ushort_t* emwB   = (ushort_t*)(W + OFF_EMWB);
  ushort_t* wihB   = (ushort_t*)(W + OFF_WIHB);
  ushort_t* w2B    = (ushort_t*)(W + OFF_W2B);
  ushort_t* mapB   = (ushort_t*)(W + OFF_MAPB);
  ushort_t* h1B    = (ushort_t*)(W + OFF_H1B);
  _Float16* Ehalf  = (_Float16*)(W + OFF_LOGITH);

  hipMemsetAsync(d_ws, 0, MEMSET_BYTES, stream);

  // one launch: prep + all bf16 conversions + kl_alpha (grid-stride, 1528 blocks)
  k_mega<<<1528, 256, 0, stream>>>(whh, muEW, lsEW, bih, bhh, wih, emapB, W1, times,
                                   muq, lsq, rho, nb, rnn, emapW, W2, W);

  // mapped = rnn @ eta_map_W^T  M=500 N=200 K=20000  (split-K atomic)
  mfma_nt<0><<<4*2*32, 256, 0, stream>>>(
      rnnB, 20000, emwB, 20000, W + OFF_MAPPED, nullptr, 200, nullptr,
      500, 200, 4, 32, 625);

  // hpre = nb @ W1[:, :V]^T  M=256 N=800 K=20000  (split-K atomic)
  mfma_nt<0><<<2*7*20, 256, 0, stream>>>(
      nbB, 20000, w1B, 20000, W + OFF_HPRE, nullptr, 800, nullptr,
      256, 800, 2, 20, 625);

  // mapped -> bf16 [512][224]
  k_conv<<<56, 256, 0, stream>>>(W + OFF_MAPPED, 200, 500, 200, mapB, 512, 224);

  // xw = mapped @ wih^T + bias2  M=500 N=800 K=224
  mfma_nt<2><<<4*7, 256, 0, stream>>>(
      mapB, 224, wihB, 224, W + OFF_XW, nullptr, 800, W + OFF_BIAS2,
      500, 800, 4, 1, 7);

  // FUSED: blocks 0..9 LSTM (reads xw), blocks 10..1579 E-GEMM 2 tiles/block (overwrites
  // union region; safe: mapped & hpre GEMMs already consumed rnnB/emwB/w1B)
  k_fused_lstm_E<<<NSRC + 1570, 512, 0, stream>>>(
      W + OFF_XW, (const u32*)(W + OFF_WHH_H), (const uint4*)(W + OFF_ETAWH),
      muEB, lsEB, W + OFF_ETAS, W, alphaB, rhoB, Ehalf);

  k_h1<<<256, 256, 0, stream>>>(W + OFF_HPRE, b1, W + OFF_W1E, W + OFF_ETAS, times, srcs, h1B);

  // h2pre = h1 @ W2^T  M=256 N=800 K=800  (split-K atomic; b2+relu folded into k_thfin)
  mfma_nt<0><<<2*7*2, 256, 0, stream>>>(
      h1B, 800, w2B, 800, W + OFF_H2, nullptr, 800, nullptr,
      256, 800, 2, 2, 25);

  k_thfin<<<256, 256, 0, stream>>>(W + OFF_H2, b2, W + OFF_ETAS, times, srcs,
                                   muthW, muthB, lsthW, lsthB, clsW, clsB,
                                   W + OFF_Z, W + OFF_WCOEF, W);

  k_nll<<<500, 256, 0, stream>>>(Ehalf, W + OFF_WCOEF, bows, W);

  k_final<<<1, 64, 0, stream>>>(W, ndocs, (float*)d_out);
}

// Round 8
// 606.662 us; speedup vs baseline: 1.4386x; 1.0096x over previous
//
#include <hip/hip_runtime.h>

typedef unsigned int u32;
typedef unsigned short ushort_t;

// problem dims
#define NTOP 50
#define NT_T 50
#define NRHO 300
#define NVOC 20000
#define NTH 800
#define NEH 200
#define NSRC 10
#define NBAT 256

// ws offsets (float units), all 8-float (32B) aligned
#define OFF_SCAL     0          // 5 accumulators
#define OFF_MAPPED   16         // 500*200 fp32 (atomic)
#define OFF_HPRE     100016     // 256*800 fp32 (atomic)
#define OFF_H2       304816     // 256*800 fp32 (atomic)
#define OFF_Z        509616     // 2500 fp32 (atomic row-sums of E)
#define OFF_DOCCNT   512120     // 50 ints
#define OFF_DOCLIST  512176     // 50*256 ints
#define MEMSET_BYTES ((size_t)524976 * 4)
#define OFF_XW       524976     // 500*800 fp32
#define OFF_BIAS2    924976     // 800
#define OFF_ETAS     925776     // 10*50*50
#define OFF_WCOEF    950776     // 256*50
#define OFF_W1E      963576     // 800*50 compact W1[:,V:]
#define OFF_WHH_H    1003576    // 80000 u32 (f16 pairs) rows of 100
#define OFF_ETAWH    1083576    // 12800 u32 (f16 pairs) rows of 128 (125 used + 3 zero)
#define OFF_H1B      1096376    // bf16 [256][800]
#define OFF_MAPB     1198776    // bf16 [512][224]
#define OFF_WIHB     1256120    // bf16 [896][224]
#define OFF_W2B      1356472    // bf16 [896][800]
#define OFF_ALPHAB   1714872    // bf16 [2560][320]
#define OFF_RHOB     2124472    // bf16 [20096][320]
#define OFF_NBB      5339832    // bf16 [256][20000]
// union: {W1B, RNNB, EMWB} reused by E (LOGITH) after mapped/hpre gemms
#define OFF_W1B      7899832    // bf16 [896][20000]
#define OFF_RNNB     16859832   // bf16 [512][20000]
#define OFF_EMWB     21979832   // bf16 [256][20000]
#define OFF_LOGITH   7899832    // f16 E [2500][20000]
// total ws: 24,539,832 floats = 98.16 MB

typedef _Float16 h2v __attribute__((ext_vector_type(2)));
typedef __bf16 bf16x8 __attribute__((ext_vector_type(8)));
typedef float f32x4 __attribute__((ext_vector_type(4)));

#define REP25(M) M(0) M(1) M(2) M(3) M(4) M(5) M(6) M(7) M(8) M(9) M(10) M(11) M(12) \
                 M(13) M(14) M(15) M(16) M(17) M(18) M(19) M(20) M(21) M(22) M(23) M(24)
#define REP7(M) M(0) M(1) M(2) M(3) M(4) M(5) M(6)

__device__ inline float dot2u(u32 a, u32 b, float c){
  h2v ha = __builtin_bit_cast(h2v, a), hb = __builtin_bit_cast(h2v, b);
#if __has_builtin(__builtin_amdgcn_fdot2)
  return __builtin_amdgcn_fdot2(ha, hb, c, false);
#else
  return c + (float)ha.x*(float)hb.x + (float)ha.y*(float)hb.y;
#endif
}

__device__ inline u32 packh2(float lo, float hi){
  h2v h; h.x = (_Float16)lo; h.y = (_Float16)hi;
  return __builtin_bit_cast(u32, h);
}

__device__ inline ushort_t f2bf(float f){
  u32 u = __builtin_bit_cast(u32, f);
  u = (u + 0x7FFFu + ((u >> 16) & 1u)) >> 16;
  return (ushort_t)u;
}

__device__ inline float fast_sig(float x){ return 1.f/(1.f + __expf(-x)); }
__device__ inline float fast_tanh(float x){ float e = __expf(2.f*x); return 1.f - 2.f/(e + 1.f); }

__device__ __forceinline__ void gl2lds16(const void* g, void* l){
  __builtin_amdgcn_global_load_lds((__attribute__((address_space(1))) void*)g,
                                   (__attribute__((address_space(3))) void*)l,
                                   16, 0, 0);
}

__device__ inline void blockReduceAdd(float v, float* red, float* target){
  int tid = threadIdx.x;
  red[tid] = v; __syncthreads();
  for (int o = blockDim.x >> 1; o > 0; o >>= 1){
    if (tid < o) red[tid] += red[tid + o];
    __syncthreads();
  }
  if (tid == 0) atomicAdd(target, red[0]);
}

// ---------------- fp32 -> bf16 16-wide chunk convert (compile-time geometry) ----------------
// dst is padded [rows..][KP16*16]; rows >= MREAL zero-filled; cols >= KUSED zero-filled.
template<int LDSRC, int MREAL, int KUSED, int KP16>
__device__ inline void conv_row16(const float* __restrict__ src, ushort_t* __restrict__ dst, int i)
{
  int row = i / KP16, cc = i - row*KP16;
  int c = cc*16;
  ushort_t* d = dst + ((size_t)row*KP16 + cc)*16;
  float v[16];
  const float* sr = src + (size_t)row*LDSRC + c;
  if (row < MREAL && c + 16 <= KUSED){
    #pragma unroll
    for (int j = 0; j < 16; j++) v[j] = sr[j];
  } else {
    #pragma unroll
    for (int j = 0; j < 16; j++){
      float x = 0.f;
      if (row < MREAL && c + j < KUSED) x = sr[j];
      v[j] = x;
    }
  }
  ushort_t o[16];
  #pragma unroll
  for (int j = 0; j < 16; j++) o[j] = f2bf(v[j]);
  *(uint4*)d = *(uint4*)o;
  *(uint4*)(d + 8) = *(uint4*)(o + 8);
}

// ---------------- mega prep/convert/klalpha kernel (grid-stride, 1528 blocks) ----------------
#define P0 64     // [0,P0)      prep items 133856
#define P1 128    // [P0,P1)     alphas chunks8 102400
#define P2 288    // [P1,P2)     rho   chunks16 20096*20
#define P3 416    // [P2,P3)     nb    chunks16 256*1250
#define P4 864    // [P3,P4)     W1    chunks16 896*1250
#define P5 1120   // [P4,P5)     rnn   chunks16 512*1250
#define P6 1248   // [P5,P6)     emw   chunks16 256*1250
#define P7 1256   // [P6,P7)     wih   chunks16 896*14
#define P8 1272   // [P7,P8)     W2    chunks16 896*50
#define P9 1528   // [P8,P9)     klalpha 750000
__global__ __launch_bounds__(256) void k_mega(
    const float* __restrict__ whh,
    const float* __restrict__ muEW, const float* __restrict__ lsEW,
    const float* __restrict__ bih, const float* __restrict__ bhh,
    const float* __restrict__ wih, const float* __restrict__ emapB,
    const float* __restrict__ W1, const int* __restrict__ times,
    const float* __restrict__ muq, const float* __restrict__ lsq,
    const float* __restrict__ rho, const float* __restrict__ nb,
    const float* __restrict__ rnn, const float* __restrict__ emapW,
    const float* __restrict__ W2f, float* __restrict__ W)
{
  int b = blockIdx.x, tid = threadIdx.x;
  __shared__ float red[256];
  if (b < P0){
    u32* whhH = (u32*)(W + OFF_WHH_H);
    u32* etaWH = (u32*)(W + OFF_ETAWH);
    for (int idx = b*256 + tid; idx < 133856; idx += P0*256){
      if (idx < 80000){
        int j = idx/100; int i = idx - j*100;
        whhH[idx] = packh2(whh[j*200 + 2*i], whh[j*200 + 2*i + 1]);
      } else if (idx < 92800){
        int d = idx - 80000; int q = d >> 7; int i = d & 127;
        u32 v = 0u;
        if (i < 125){
          const float* src = (q < 50) ? (muEW + q*250) : (lsEW + (q-50)*250);
          v = packh2(src[2*i], src[2*i+1]);
        }
        etaWH[d] = v;
      } else if (idx < 93600){
        int j = idx - 92800;
        float acc = bih[j] + bhh[j];
        const float* wr = wih + (size_t)j*200;
        #pragma unroll 4
        for (int k = 0; k < 200; k++) acc += emapB[k]*wr[k];
        W[OFF_BIAS2 + j] = acc;
      } else if (idx < 133600){
        int d = idx - 93600; int j = d/50; int k = d - j*50;
        W[OFF_W1E + d] = W1[(size_t)j*20050 + 20000 + k];
      } else {
        int bb = idx - 133600; int t = times[bb];
        int* docCnt = (int*)(W + OFF_DOCCNT);
        int* docList = (int*)(W + OFF_DOCLIST);
        int pos = atomicAdd(&docCnt[t], 1);
        docList[t*256 + pos] = bb;
      }
    }
  } else if (b < P1){
    // alphas permute+pad: dst[t*50+k][r] = muq[k][t][r]; [2560][320] bf16, chunks of 8
    ushort_t* dst = (ushort_t*)(W + OFF_ALPHAB);
    for (int idx = (b-P0)*256 + tid; idx < 102400; idx += (P1-P0)*256){
      int row = idx / 40, c = (idx - row*40) << 3;
      ushort_t out[8];
      const float* src = nullptr;
      if (row < 2500){ int t = row/50, k = row - t*50; src = muq + (size_t)k*15000 + t*300; }
      #pragma unroll
      for (int j = 0; j < 8; j++){
        int r = c + j;
        float v = (src && r < 300) ? src[r] : 0.f;
        out[j] = f2bf(v);
      }
      *(uint4*)(dst + (size_t)row*320 + c) = *(uint4*)out;
    }
  } else if (b < P2){
    ushort_t* dst = (ushort_t*)(W + OFF_RHOB);
    #pragma unroll 2
    for (int i = (b-P1)*256 + tid; i < 20096*20; i += (P2-P1)*256)
      conv_row16<300, 20000, 300, 20>(rho, dst, i);
  } else if (b < P3){
    ushort_t* dst = (ushort_t*)(W + OFF_NBB);
    #pragma unroll 2
    for (int i = (b-P2)*256 + tid; i < 256*1250; i += (P3-P2)*256)
      conv_row16<20000, 256, 20000, 1250>(nb, dst, i);
  } else if (b < P4){
    ushort_t* dst = (ushort_t*)(W + OFF_W1B);
    #pragma unroll 2
    for (int i = (b-P3)*256 + tid; i < 896*1250; i += (P4-P3)*256)
      conv_row16<20050, 800, 20000, 1250>(W1, dst, i);
  } else if (b < P5){
    ushort_t* dst = (ushort_t*)(W + OFF_RNNB);
    #pragma unroll 2
    for (int i = (b-P4)*256 + tid; i < 512*1250; i += (P5-P4)*256)
      conv_row16<20000, 500, 20000, 1250>(rnn, dst, i);
  } else if (b < P6){
    ushort_t* dst = (ushort_t*)(W + OFF_EMWB);
    #pragma unroll 2
    for (int i = (b-P5)*256 + tid; i < 256*1250; i += (P6-P5)*256)
      conv_row16<20000, 200, 20000, 1250>(emapW, dst, i);
  } else if (b < P7){
    ushort_t* dst = (ushort_t*)(W + OFF_WIHB);
    #pragma unroll 2
    for (int i = (b-P6)*256 + tid; i < 896*14; i += (P7-P6)*256)
      conv_row16<200, 800, 200, 14>(wih, dst, i);
  } else if (b < P8){
    ushort_t* dst = (ushort_t*)(W + OFF_W2B);
    #pragma unroll 2
    for (int i = (b-P7)*256 + tid; i < 896*50; i += (P8-P7)*256)
      conv_row16<800, 800, 800, 50>(W2f, dst, i);
  } else {
    // kl_alpha
    const float inv_dl = 1.f/(0.005f + 1e-6f);
    const float logdl = -5.2983173665480363f;
    float local = 0.f;
    for (int idx = (b-P8)*256 + tid; idx < 750000; idx += (P9-P8)*256){
      int rem = idx % 15000; int t = rem / 300;
      float ls = lsq[idx]; float mu = muq[idx];
      if (t == 0){
        local += 0.5f*((__expf(ls) + mu*mu)/(1.f + 1e-6f) - 1.f - ls);
      } else {
        float d = mu - muq[idx - 300];
        local += 0.5f*((__expf(ls) + d*d)*inv_dl - 1.f + logdl - ls);
      }
    }
    blockReduceAdd(local, red, W + OFF_SCAL + 1);
  }
}

// ---------------- small fp32 -> bf16 convert (for mapped, after its GEMM) ----------------
__device__ inline void conv_seg(const float* __restrict__ src, int ldsrc,
                                int Mreal, int Kused,
                                ushort_t* __restrict__ dst, int Kp, int idx)
{
  int kb = Kp >> 3;
  int row = idx / kb, c = (idx - row*kb) << 3;
  ushort_t out[8];
  #pragma unroll
  for (int j = 0; j < 8; j++){
    float v = 0.f;
    int k = c + j;
    if (row < Mreal && k < Kused) v = src[(size_t)row*ldsrc + k];
    out[j] = f2bf(v);
  }
  *(uint4*)(dst + (size_t)row*Kp + c) = *(uint4*)out;
}

__global__ __launch_bounds__(256) void k_conv(const float* __restrict__ src, int ldsrc,
                                              int Mreal, int Kused,
                                              ushort_t* __restrict__ dst, int Mp, int Kp)
{
  int idx = blockIdx.x*256 + threadIdx.x;
  int kb = Kp >> 3;
  if (idx >= Mp*kb) return;
  conv_seg(src, ldsrc, Mreal, Kused, dst, Kp, idx);
}

// ---------------- bf16 MFMA NT GEMM: C[M,N] = A[M,K] . B[N,K]^T ----------------
// MODE 0: atomic f32; MODE 2: f32 store + col-bias.
// K-loop: 2-deep LDS double-buffer, issue-early/wait-late.
template<int MODE>
__global__ __launch_bounds__(256) void mfma_nt(
    const ushort_t* __restrict__ A, int lda,
    const ushort_t* __restrict__ B, int ldb,
    float* __restrict__ C, _Float16* __restrict__ Ch, int ldc,
    const float* __restrict__ nBias,
    int M, int N, int mT, int kS, int chunks)
{
  __shared__ __align__(16) ushort_t As[2][128*32];
  __shared__ __align__(16) ushort_t Bs[2][128*32];
  int bid = blockIdx.x;
  int kIdx = bid % kS; int rest = bid / kS;
  int mIdx = rest % mT; int nIdx = rest / mT;
  int tid = threadIdx.x;
  int w = tid >> 6, l = tid & 63;
  int c0 = (int)(((long long)chunks * kIdx) / kS);
  int c1 = (int)(((long long)chunks * (kIdx+1)) / kS);
  int r0 = w*32;
  const ushort_t* ga0 = A + (size_t)(mIdx*128 + r0      + (l>>2))*lda + (l&3)*8;
  const ushort_t* ga1 = A + (size_t)(mIdx*128 + r0 + 16 + (l>>2))*lda + (l&3)*8;
  const ushort_t* gb0 = B + (size_t)(nIdx*128 + r0      + (l>>2))*ldb + (l&3)*8;
  const ushort_t* gb1 = B + (size_t)(nIdx*128 + r0 + 16 + (l>>2))*ldb + (l&3)*8;
  int wr = (w >> 1)*64, wc = (w & 1)*64;
  int lr = l & 15, lq = l >> 4;
  f32x4 acc[4][4];
  #pragma unroll
  for (int i = 0; i < 4; i++)
    #pragma unroll
    for (int j = 0; j < 4; j++)
      acc[i][j] = (f32x4)0.f;

  {
    size_t ko = (size_t)c0 * 32;
    gl2lds16(ga0 + ko, As[0] + r0*32);
    gl2lds16(ga1 + ko, As[0] + r0*32 + 512);
    gl2lds16(gb0 + ko, Bs[0] + r0*32);
    gl2lds16(gb1 + ko, Bs[0] + r0*32 + 512);
  }
  asm volatile("s_waitcnt vmcnt(0)" ::: "memory");
  __builtin_amdgcn_s_barrier();

  int cur = 0;
  for (int c = c0; c < c1; c++){
    if (c + 1 < c1){
      size_t ko = (size_t)(c + 1) * 32;
      int nxt = cur ^ 1;
      gl2lds16(ga0 + ko, As[nxt] + r0*32);
      gl2lds16(ga1 + ko, As[nxt] + r0*32 + 512);
      gl2lds16(gb0 + ko, Bs[nxt] + r0*32);
      gl2lds16(gb1 + ko, Bs[nxt] + r0*32 + 512);
    }
    bf16x8 av[4], bv[4];
    #pragma unroll
    for (int i = 0; i < 4; i++)
      av[i] = *(const bf16x8*)(As[cur] + (wr + i*16 + lr)*32 + lq*8);
    #pragma unroll
    for (int j = 0; j < 4; j++)
      bv[j] = *(const bf16x8*)(Bs[cur] + (wc + j*16 + lr)*32 + lq*8);
    #pragma unroll
    for (int i = 0; i < 4; i++)
      #pragma unroll
      for (int j = 0; j < 4; j++)
        acc[i][j] = __builtin_amdgcn_mfma_f32_16x16x32_bf16(av[i], bv[j], acc[i][j], 0, 0, 0);
    asm volatile("s_waitcnt vmcnt(0)" ::: "memory");
    __builtin_amdgcn_s_barrier();
    cur ^= 1;
  }
  #pragma unroll
  for (int i = 0; i < 4; i++){
    #pragma unroll
    for (int r = 0; r < 4; r++){
      int row = mIdx*128 + wr + i*16 + lq*4 + r;
      if (row >= M) continue;
      #pragma unroll
      for (int j = 0; j < 4; j++){
        int col = nIdx*128 + wc + j*16 + lr;
        if (col >= N) continue;
        float v = acc[i][j][r];
        if (MODE == 0)      atomicAdd(&C[(size_t)row*ldc + col], v);
        else                C[(size_t)row*ldc + col] = v + nBias[col];
      }
    }
  }
}

// ---------------- FUSED: LSTM+eta (blocks 0..9) || E-GEMM exp(alpha.rho^T) (blocks 10..799) ----
// LSTM part verbatim (512 threads). E part: ONE 256x256 tile per 512-thread block (8 waves,
// each owns a 128x64 quadrant: wr=(w>>2)*128, wc=(w&3)*64, acc[8][4]). vs round 7's 2x128x128:
// staged traffic halves (790 tiles x 320KB = 253MB vs 515MB), MFMA per wave per chunk doubles
// (16->32, better latency cover), barrier rounds halve. LDS 64KB tiles (same), 2 blocks/CU.
// alphaB padded to 2560 = 10*256 exactly; rhoB reads past row 20096 stay inside ws (nbB region)
// and feed only col>=20000-guarded outputs. Numerics per element unchanged (same chunk order).
// __launch_bounds__(512, 2): VGPR cap 256 (round 6's (512,4) cap 128 caused spill collapse).
__global__ __launch_bounds__(512, 2) void k_fused_lstm_E(
    const float* __restrict__ xw, const u32* __restrict__ whhH, const uint4* __restrict__ etaW4,
    const float* __restrict__ muEB, const float* __restrict__ lsEB,
    float* __restrict__ etas, float* __restrict__ W,
    const ushort_t* __restrict__ A, const ushort_t* __restrict__ B,
    _Float16* __restrict__ Ch)
{
  __shared__ __align__(16) ushort_t As[2][256*32];  // [dbuf] 16KB each
  __shared__ __align__(16) ushort_t Bs[2][256*32];
  __shared__ uint4 hp4[2][32];
  __shared__ float zbuf[800];
  __shared__ float red[512];

  if (blockIdx.x < NSRC){
    // ================= LSTM + eta recurrence =================
    int s = blockIdx.x; int tid = threadIdx.x;
    uint4 z4; z4.x = z4.y = z4.z = z4.w = 0u;
#define DECLW(i) uint4 wa##i = z4, wb##i = z4;
    REP25(DECLW)
#undef DECLW
    float ebias = 0.f;
    if (tid < 400){
      const uint4* ra = (const uint4*)(whhH + tid*100);
      const uint4* rb = (const uint4*)(whhH + (tid + 400)*100);
#define LDW(i) wa##i = ra[i]; wb##i = rb[i];
      REP25(LDW)
#undef LDW
    } else if (tid < 500){
      int q = tid - 400;
      const uint4* re = etaW4 + q*32;
#define LDA(i) wa##i = re[i];
      REP25(LDA)
#undef LDA
#define LDB(i) wb##i = re[25+i];
      REP7(LDB)
#undef LDB
      ebias = (q < 50) ? muEB[q] : lsEB[q - 50];
    }
    float creg = 0.f, muPrev = 0.f, klLocal = 0.f;
    if (tid < 64) ((uint4*)hp4)[tid] = z4;
    __syncthreads();
    const float inv_dl = 1.f/(0.005f + 1e-6f);
    const float logdl = -5.2983173665480363f;

    for (int t = 0; t < NT_T; t++){
      const uint4* hc = hp4[t & 1];
      uint4* hn = hp4[(t + 1) & 1];
      if (tid < 400){
        float a0=0.f,a1=0.f,a2=0.f,a3=0.f,b0=0.f,b1=0.f,b2=0.f,b3=0.f;
#define DOT(i) { uint4 h = hc[i]; \
        a0 = dot2u(wa##i.x, h.x, a0); a1 = dot2u(wa##i.y, h.y, a1); \
        a2 = dot2u(wa##i.z, h.z, a2); a3 = dot2u(wa##i.w, h.w, a3); \
        b0 = dot2u(wb##i.x, h.x, b0); b1 = dot2u(wb##i.y, h.y, b1); \
        b2 = dot2u(wb##i.z, h.z, b2); b3 = dot2u(wb##i.w, h.w, b3); }
        REP25(DOT)
#undef DOT
        const float* xr = xw + (size_t)(s*50 + t)*800;
        zbuf[tid]       = ((a0+a1)+(a2+a3)) + xr[tid];
        zbuf[tid + 400] = ((b0+b1)+(b2+b3)) + xr[tid + 400];
      }
      __syncthreads();  // B1: zbuf ready
      if (tid < 200){
        float zi = zbuf[tid], zf = zbuf[200+tid], zg = zbuf[400+tid], zo = zbuf[600+tid];
        float ig = fast_sig(zi);
        float fg = fast_sig(zf);
        float gg = fast_tanh(zg);
        float og = fast_sig(zo);
        creg = fg*creg + ig*gg;
        float hv = og*fast_tanh(creg);
        ((_Float16*)hn)[tid] = (_Float16)hv;
      }
      __syncthreads();  // B2: h_t ready
      if (tid >= 400 && tid < 500){
        float e0 = ebias, e1 = 0.f, e2 = 0.f, e3 = 0.f;
#define DOTE(i) { uint4 h = hn[i]; \
        e0 = dot2u(wa##i.x, h.x, e0); e1 = dot2u(wa##i.y, h.y, e1); \
        e2 = dot2u(wa##i.z, h.z, e2); e3 = dot2u(wa##i.w, h.w, e3); }
        REP25(DOTE)
#undef DOTE
#define DOTP(i) { uint4 h = hc[25+i]; \
        e0 = dot2u(wb##i.x, h.x, e0); e1 = dot2u(wb##i.y, h.y, e1); \
        e2 = dot2u(wb##i.z, h.z, e2); e3 = dot2u(wb##i.w, h.w, e3); }
        REP7(DOTP)
#undef DOTP
        float eacc = (e0+e1)+(e2+e3);
        int q = tid - 400;
        if (q < 50){
          float mu = eacc;
          etas[(size_t)(s*50 + t)*50 + q] = mu;
          if (t == 0) klLocal += 0.5f*mu*mu/(1.f + 1e-6f);
          else { float d = mu - muPrev; klLocal += 0.5f*d*d*inv_dl; }
          muPrev = mu;
          ((_Float16*)hn)[200 + q] = (_Float16)mu;
        } else {
          float ls = eacc;
          if (t == 0) klLocal += 0.5f*(__expf(ls)/(1.f + 1e-6f) - 1.f - ls);
          else {
            ls = fminf(fmaxf(ls, -10.f), 10.f);
            klLocal += 0.5f*(__expf(ls)*inv_dl - 1.f + logdl - ls);
          }
        }
      }
    }
    __syncthreads();
    blockReduceAdd(klLocal, red, W + OFF_SCAL + 2);
  } else {
    // ================= E-GEMM (MODE 3), one 256x256 tile per block =================
    int tid = threadIdx.x;
    int v = blockIdx.x - NSRC;                  // tile id in [0, 790)
    int mIdx = v % 10; int nIdx = v / 10;       // m-fast for B-panel L2 reuse
    const int M = 2500, N = 20000, ldc = 20000;
    int w = tid >> 6, l = tid & 63;
    int r0 = w*32;
    const ushort_t* ga0 = A + (size_t)(mIdx*256 + r0      + (l>>2))*320 + (l&3)*8;
    const ushort_t* ga1 = A + (size_t)(mIdx*256 + r0 + 16 + (l>>2))*320 + (l&3)*8;
    const ushort_t* gb0 = B + (size_t)(nIdx*256 + r0      + (l>>2))*320 + (l&3)*8;
    const ushort_t* gb1 = B + (size_t)(nIdx*256 + r0 + 16 + (l>>2))*320 + (l&3)*8;
    int wr = (w >> 2)*128, wc = (w & 3)*64;
    int lr = l & 15, lq = l >> 4;
    f32x4 acc[8][4];
    #pragma unroll
    for (int i = 0; i < 8; i++)
      #pragma unroll
      for (int j = 0; j < 4; j++)
        acc[i][j] = (f32x4)0.f;

    gl2lds16(ga0, As[0] + r0*32);
    gl2lds16(ga1, As[0] + r0*32 + 512);
    gl2lds16(gb0, Bs[0] + r0*32);
    gl2lds16(gb1, Bs[0] + r0*32 + 512);
    asm volatile("s_waitcnt vmcnt(0)" ::: "memory");
    __builtin_amdgcn_s_barrier();

    int cur = 0;
    for (int c = 0; c < 10; c++){
      if (c + 1 < 10){
        size_t ko = (size_t)(c + 1) * 32;
        int nxt = cur ^ 1;
        gl2lds16(ga0 + ko, As[nxt] + r0*32);
        gl2lds16(ga1 + ko, As[nxt] + r0*32 + 512);
        gl2lds16(gb0 + ko, Bs[nxt] + r0*32);
        gl2lds16(gb1 + ko, Bs[nxt] + r0*32 + 512);
      }
      bf16x8 bv[4];
      #pragma unroll
      for (int j = 0; j < 4; j++)
        bv[j] = *(const bf16x8*)(Bs[cur] + (wc + j*16 + lr)*32 + lq*8);
      #pragma unroll
      for (int i = 0; i < 8; i++){
        bf16x8 av = *(const bf16x8*)(As[cur] + (wr + i*16 + lr)*32 + lq*8);
        #pragma unroll
        for (int j = 0; j < 4; j++)
          acc[i][j] = __builtin_amdgcn_mfma_f32_16x16x32_bf16(av, bv[j], acc[i][j], 0, 0, 0);
      }
      asm volatile("s_waitcnt vmcnt(0)" ::: "memory");
      __builtin_amdgcn_s_barrier();
      cur ^= 1;
    }
    float* Z = W + OFF_Z;
    #pragma unroll
    for (int i = 0; i < 8; i++){
      #pragma unroll
      for (int r = 0; r < 4; r++){
        int row = mIdx*256 + wr + i*16 + lq*4 + r;
        float p = 0.f;
        if (row < M){
          #pragma unroll
          for (int j = 0; j < 4; j++){
            int col = nIdx*256 + wc + j*16 + lr;
            if (col < N){
              float e = __expf(acc[i][j][r]);
              Ch[(size_t)row*ldc + col] = (_Float16)e;
              p += e;
            }
          }
        }
        p += __shfl_xor(p, 1, 16);
        p += __shfl_xor(p, 2, 16);
        p += __shfl_xor(p, 4, 16);
        p += __shfl_xor(p, 8, 16);
        if (lr == 0 && row < M) atomicAdd(&Z[row], p);
      }
    }
  }
}

// ---------------- h1 = relu(hpre + b1 + eta_std @ W1E^T) -> bf16 ----------------
__global__ __launch_bounds__(256) void k_h1(
    const float* __restrict__ hpre, const float* __restrict__ b1, const float* __restrict__ w1e,
    const float* __restrict__ etas, const int* __restrict__ times, const int* __restrict__ srcs,
    ushort_t* __restrict__ h1B)
{
  int b = blockIdx.x, tid = threadIdx.x;
  __shared__ float et[50];
  int tb = times[b], sb = srcs[b];
  if (tid < 50) et[tid] = etas[(size_t)(sb*50 + tb)*50 + tid];
  __syncthreads();
  for (int j = tid; j < 800; j += 256){
    float acc = hpre[(size_t)b*800 + j] + b1[j];
    const float* wrow = w1e + (size_t)j*50;
    #pragma unroll
    for (int k = 0; k < 50; k++) acc += et[k]*wrow[k];
    h1B[(size_t)b*800 + j] = f2bf(fmaxf(acc, 0.f));
  }
}

// ---------------- theta head (h2pre + b2, relu folded; wcoef = theta/Z) ----------------
__global__ __launch_bounds__(256) void k_thfin(
    const float* __restrict__ h2g, const float* __restrict__ b2, const float* __restrict__ etas,
    const int* __restrict__ times, const int* __restrict__ srcs,
    const float* __restrict__ muW, const float* __restrict__ muB,
    const float* __restrict__ lsW, const float* __restrict__ lsB,
    const float* __restrict__ clsW, const float* __restrict__ clsB,
    const float* __restrict__ Zrow, float* __restrict__ wcoef, float* __restrict__ W)
{
  int b = blockIdx.x, tid = threadIdx.x;
  __shared__ float h2s[800], mu[50], lsv[50], et[50], th[50], lg[10], red[64], shm[2];
  for (int j = tid; j < 800; j += 256) h2s[j] = fmaxf(h2g[(size_t)b*800 + j] + b2[j], 0.f);
  int tb = times[b], sb = srcs[b];
  if (tid < 50) et[tid] = etas[(size_t)(sb*50 + tb)*50 + tid];
  __syncthreads();
  if (tid < 100){
    int q = (tid < 50) ? tid : tid - 50;
    const float* w = (tid < 50) ? (muW + (size_t)q*800) : (lsW + (size_t)q*800);
    float acc = (tid < 50) ? muB[q] : lsB[q];
    #pragma unroll 8
    for (int j = 0; j < 800; j++) acc += h2s[j]*w[j];
    if (tid < 50) mu[q] = acc;
    else lsv[q] = fminf(fmaxf(acc, -10.f), 10.f);
  }
  __syncthreads();
  if (tid == 0){ float m = -1e30f; for (int k = 0; k < 50; k++) m = fmaxf(m, mu[k]); shm[0] = m; }
  __syncthreads();
  if (tid < 50) th[tid] = __expf(mu[tid] - shm[0]);
  __syncthreads();
  if (tid == 0){ float z = 0.f; for (int k = 0; k < 50; k++) z += th[k]; shm[1] = z; }
  __syncthreads();
  if (tid < 64) red[tid] = 0.f;
  if (tid < 50){
    float t_ = th[tid]/shm[1]; th[tid] = t_;
    wcoef[(size_t)b*50 + tid] = t_/Zrow[tb*50 + tid];
    float d = mu[tid] - et[tid];
    red[tid] = 0.5f*((__expf(lsv[tid]) + d*d)/(1.f + 1e-6f) - 1.f - lsv[tid]);
  }
  __syncthreads();
  if (tid < 10){
    float a = clsB[tid];
    #pragma unroll
    for (int k = 0; k < 50; k++) a += th[k]*clsW[tid*50 + k];
    lg[tid] = a;
  }
  __syncthreads();
  if (tid == 0){
    float m = -1e30f; for (int i = 0; i < 10; i++) m = fmaxf(m, lg[i]);
    float z = 0.f; for (int i = 0; i < 10; i++) z += __expf(lg[i] - m);
    float lse = m + __logf(z);
    atomicAdd(W + OFF_SCAL + 4, lse - lg[sb]);
    float ssum = 0.f; for (int i = 0; i < 50; i++) ssum += red[i];
    atomicAdd(W + OFF_SCAL + 3, ssum);
  }
}

// ---------------- nll: E already exponentiated ----------------
__global__ __launch_bounds__(256) void k_nll(
    const _Float16* __restrict__ E, const float* __restrict__ wcoef,
    const float* __restrict__ bows, float* __restrict__ W)
{
  int t = blockIdx.x/10, vc = blockIdx.x%10;
  int v0 = vc*2000;
  int tid = threadIdx.x;
  const int* docCnt = (const int*)(W + OFF_DOCCNT);
  const int* docList = (const int*)(W + OFF_DOCLIST);
  __shared__ float wch[64*50];
  __shared__ int ids[64];
  __shared__ float red[256];
  int nd = docCnt[t];
  float acc = 0.f;
  for (int d0 = 0; d0 < nd; d0 += 64){
    int ndc = min(64, nd - d0);
    __syncthreads();
    for (int i = tid; i < ndc*50; i += 256){
      int d = i/50, k = i - d*50;
      int bb = docList[t*256 + d0 + d];
      if (k == 0) ids[d] = bb;
      wch[i] = wcoef[(size_t)bb*50 + k];
    }
    __syncthreads();
    for (int v = v0 + tid; v < v0 + 2000; v += 256){
      float e[50];
      #pragma unroll
      for (int k = 0; k < 50; k++)
        e[k] = (float)E[(size_t)(t*50 + k)*NVOC + v];
      for (int d = 0; d < ndc; d++){
        float s = 0.f;
        #pragma unroll
        for (int k = 0; k < 50; k++) s += wch[d*50 + k]*e[k];
        acc += bows[(size_t)ids[d]*NVOC + v]*__logf(s);
      }
    }
  }
  __syncthreads();
  blockReduceAdd(acc, red, W + OFF_SCAL + 0);
}

// ---------------- finalize ----------------
__global__ void k_final(const float* __restrict__ W, const int* __restrict__ ndocs, float* __restrict__ out)
{
  if (blockIdx.x == 0 && threadIdx.x == 0){
    float coeff = (float)ndocs[0] / 256.f;
    const float* scal = W + OFF_SCAL;
    float nll  = -scal[0]*coeff;
    float kla  = scal[1];
    float kle  = scal[2];
    float klth = scal[3]*coeff;
    float pred = scal[4]*coeff;
    out[0] = nll + kla + kle + klth + pred;
    out[1] = nll; out[2] = kla; out[3] = kle; out[4] = klth; out[5] = pred;
  }
}

extern "C" void kernel_launch(void* const* d_in, const int* in_sizes, int n_in,
                              void* d_out, int out_size, void* d_ws, size_t ws_size,
                              hipStream_t stream)
{
  (void)in_sizes; (void)n_in; (void)out_size; (void)ws_size;
  const float* bows  = (const float*)d_in[1];
  const float* nb    = (const float*)d_in[2];
  const int*   times = (const int*)d_in[3];
  const int*   srcs  = (const int*)d_in[4];
  const float* rnn   = (const float*)d_in[5];
  const int*   ndocs = (const int*)d_in[6];
  const float* muq   = (const float*)d_in[7];
  const float* lsq   = (const float*)d_in[8];
  const float* rho   = (const float*)d_in[9];
  const float* W1    = (const float*)d_in[10];
  const float* b1    = (const float*)d_in[11];
  const float* W2    = (const float*)d_in[12];
  const float* b2    = (const float*)d_in[13];
  const float* muthW = (const float*)d_in[14];
  const float* muthB = (const float*)d_in[15];
  const float* lsthW = (const float*)d_in[16];
  const float* lsthB = (const float*)d_in[17];
  const float* emapW = (const float*)d_in[18];
  const float* emapB = (const float*)d_in[19];
  const float* wih   = (const float*)d_in[20];
  const float* whh   = (const float*)d_in[21];
  const float* bih   = (const float*)d_in[22];
  const float* bhh   = (const float*)d_in[23];
  const float* muEW  = (const float*)d_in[24];
  const float* muEB  = (const float*)d_in[25];
  const float* lsEW  = (const float*)d_in[26];
  const float* lsEB  = (const float*)d_in[27];
  const float* clsW  = (const float*)d_in[28];
  const float* clsB  = (const float*)d_in[29];

  float* W = (float*)d_ws;
  ushort_t* alphaB = (ushort_t*)(W + OFF_ALPHAB);
  ushort_t* rhoB   = (ushort_t*)(W + OFF_RHOB);
  ushort_t* nbB    = (ushort_t*)(W + OFF_NBB);
  ushort_t* w1B    = (ushort_t*)(W + OFF_W1B);
  ushort_t* rnnB   = (ushort_t*)(W + OFF_RNNB);
  ushort_t* emwB   = (ushort_t*)(W + OFF_EMWB);
  ushort_t* wihB   = (ushort_t*)(W + OFF_WIHB);
  ushort_t* w2B    = (ushort_t*)(W + OFF_W2B);
  ushort_t* mapB   = (ushort_t*)(W + OFF_MAPB);
  ushort_t* h1B    = (ushort_t*)(W + OFF_H1B);
  _Float16* Ehalf  = (_Float16*)(W + OFF_LOGITH);

  hipMemsetAsync(d_ws, 0, MEMSET_BYTES, stream);

  // one launch: prep + all bf16 conversions + kl_alpha (grid-stride, 1528 blocks)
  k_mega<<<1528, 256, 0, stream>>>(whh, muEW, lsEW, bih, bhh, wih, emapB, W1, times,
                                   muq, lsq, rho, nb, rnn, emapW, W2, W);

  // mapped = rnn @ eta_map_W^T  M=500 N=200 K=20000  (split-K atomic)
  mfma_nt<0><<<4*2*32, 256, 0, stream>>>(
      rnnB, 20000, emwB, 20000, W + OFF_MAPPED, nullptr, 200, nullptr,
      500, 200, 4, 32, 625);

  // hpre = nb @ W1[:, :V]^T  M=256 N=800 K=20000  (split-K atomic)
  mfma_nt<0><<<2*7*20, 256, 0, stream>>>(
      nbB, 20000, w1B, 20000, W + OFF_HPRE, nullptr, 800, nullptr,
      256, 800, 2, 20, 625);

  // mapped -> bf16 [512][224]
  k_conv<<<56, 256, 0, stream>>>(W + OFF_MAPPED, 200, 500, 200, mapB, 512, 224);

  // xw = mapped @ wih^T + bias2  M=500 N=800 K=224
  mfma_nt<2><<<4*7, 256, 0, stream>>>(
      mapB, 224, wihB, 224, W + OFF_XW, nullptr, 800, W + OFF_BIAS2,
      500, 800, 4, 1, 7);

  // FUSED: blocks 0..9 LSTM (reads xw), blocks 10..799 E-GEMM 256x256/block (overwrites
  // union region; safe: mapped & hpre GEMMs already consumed rnnB/emwB/w1B)
  k_fused_lstm_E<<<NSRC + 790, 512, 0, stream>>>(
      W + OFF_XW, (const u32*)(W + OFF_WHH_H), (const uint4*)(W + OFF_ETAWH),
      muEB, lsEB, W + OFF_ETAS, W, alphaB, rhoB, Ehalf);

  k_h1<<<256, 256, 0, stream>>>(W + OFF_HPRE, b1, W + OFF_W1E, W + OFF_ETAS, times, srcs, h1B);

  // h2pre = h1 @ W2^T  M=256 N=800 K=800  (split-K atomic; b2+relu folded into k_thfin)
  mfma_nt<0><<<2*7*2, 256, 0, stream>>>(
      h1B, 800, w2B, 800, W + OFF_H2, nullptr, 800, nullptr,
      256, 800, 2, 2, 25);

  k_thfin<<<256, 256, 0, stream>>>(W + OFF_H2, b2, W + OFF_ETAS, times, srcs,
                                   muthW, muthB, lsthW, lsthB, clsW, clsB,
                                   W + OFF_Z, W + OFF_WCOEF, W);

  k_nll<<<500, 256, 0, stream>>>(Ehalf, W + OFF_WCOEF, bows, W);

  k_final<<<1, 64, 0, stream>>>(W, ndocs, (float*)d_out);
}

// Round 9
// 589.425 us; speedup vs baseline: 1.4806x; 1.0292x over previous
//
#include <hip/hip_runtime.h>

typedef unsigned int u32;
typedef unsigned short ushort_t;

// problem dims
#define NTOP 50
#define NT_T 50
#define NRHO 300
#define NVOC 20000
#define NTH 800
#define NEH 200
#define NSRC 10
#define NBAT 256

// ws offsets (float units), all 8-float (32B) aligned
#define OFF_SCAL     0          // 5 accumulators
#define OFF_MAPPED   16         // 500*200 fp32 (atomic)
#define OFF_HPRE     100016     // 256*800 fp32 (atomic)
#define OFF_H2       304816     // 256*800 fp32 (atomic)
#define OFF_Z        509616     // 2500 fp32 (atomic row-sums of E)
#define OFF_DOCCNT   512120     // 50 ints
#define OFF_DOCLIST  512176     // 50*256 ints
#define MEMSET_BYTES ((size_t)524976 * 4)
#define OFF_XW       524976     // 500*800 fp32
#define OFF_BIAS2    924976     // 800
#define OFF_ETAS     925776     // 10*50*50
#define OFF_WCOEF    950776     // 256*50
#define OFF_W1E      963576     // 800*50 compact W1[:,V:]
#define OFF_WHH_H    1003576    // 80000 u32 (f16 pairs) rows of 100
#define OFF_ETAWH    1083576    // 12800 u32 (f16 pairs) rows of 128 (125 used + 3 zero)
#define OFF_H1B      1096376    // bf16 [256][800]
#define OFF_MAPB     1198776    // bf16 [512][224]
#define OFF_WIHB     1256120    // bf16 [896][224]
#define OFF_W2B      1356472    // bf16 [896][800]
#define OFF_ALPHAB   1714872    // bf16 [2560][320]
#define OFF_RHOB     2124472    // bf16 [20096][320]
#define OFF_NBB      5339832    // bf16 [256][20000]
// union: {W1B, RNNB, EMWB} reused by E (LOGITH) after mapped/hpre gemms
#define OFF_W1B      7899832    // bf16 [896][20000]
#define OFF_RNNB     16859832   // bf16 [512][20000]
#define OFF_EMWB     21979832   // bf16 [256][20000]
#define OFF_LOGITH   7899832    // f16 E [2500][20000]
// total ws: 24,539,832 floats = 98.16 MB

typedef _Float16 h2v __attribute__((ext_vector_type(2)));
typedef __bf16 bf16x8 __attribute__((ext_vector_type(8)));
typedef float f32x4 __attribute__((ext_vector_type(4)));

#define REP25(M) M(0) M(1) M(2) M(3) M(4) M(5) M(6) M(7) M(8) M(9) M(10) M(11) M(12) \
                 M(13) M(14) M(15) M(16) M(17) M(18) M(19) M(20) M(21) M(22) M(23) M(24)
#define REP7(M) M(0) M(1) M(2) M(3) M(4) M(5) M(6)

__device__ inline float dot2u(u32 a, u32 b, float c){
  h2v ha = __builtin_bit_cast(h2v, a), hb = __builtin_bit_cast(h2v, b);
#if __has_builtin(__builtin_amdgcn_fdot2)
  return __builtin_amdgcn_fdot2(ha, hb, c, false);
#else
  return c + (float)ha.x*(float)hb.x + (float)ha.y*(float)hb.y;
#endif
}

__device__ inline u32 packh2(float lo, float hi){
  h2v h; h.x = (_Float16)lo; h.y = (_Float16)hi;
  return __builtin_bit_cast(u32, h);
}

__device__ inline ushort_t f2bf(float f){
  u32 u = __builtin_bit_cast(u32, f);
  u = (u + 0x7FFFu + ((u >> 16) & 1u)) >> 16;
  return (ushort_t)u;
}

__device__ inline float fast_sig(float x){ return 1.f/(1.f + __expf(-x)); }
__device__ inline float fast_tanh(float x){ float e = __expf(2.f*x); return 1.f - 2.f/(e + 1.f); }

__device__ __forceinline__ void gl2lds16(const void* g, void* l){
  __builtin_amdgcn_global_load_lds((__attribute__((address_space(1))) void*)g,
                                   (__attribute__((address_space(3))) void*)l,
                                   16, 0, 0);
}

__device__ inline void blockReduceAdd(float v, float* red, float* target){
  int tid = threadIdx.x;
  red[tid] = v; __syncthreads();
  for (int o = blockDim.x >> 1; o > 0; o >>= 1){
    if (tid < o) red[tid] += red[tid + o];
    __syncthreads();
  }
  if (tid == 0) atomicAdd(target, red[0]);
}

// ---------------- fp32 -> bf16 16-wide chunk convert (compile-time geometry) ----------------
// dst is padded [rows..][KP16*16]; rows >= MREAL zero-filled; cols >= KUSED zero-filled.
template<int LDSRC, int MREAL, int KUSED, int KP16>
__device__ inline void conv_row16(const float* __restrict__ src, ushort_t* __restrict__ dst, int i)
{
  int row = i / KP16, cc = i - row*KP16;
  int c = cc*16;
  ushort_t* d = dst + ((size_t)row*KP16 + cc)*16;
  float v[16];
  const float* sr = src + (size_t)row*LDSRC + c;
  if (row < MREAL && c + 16 <= KUSED){
    #pragma unroll
    for (int j = 0; j < 16; j++) v[j] = sr[j];
  } else {
    #pragma unroll
    for (int j = 0; j < 16; j++){
      float x = 0.f;
      if (row < MREAL && c + j < KUSED) x = sr[j];
      v[j] = x;
    }
  }
  ushort_t o[16];
  #pragma unroll
  for (int j = 0; j < 16; j++) o[j] = f2bf(v[j]);
  *(uint4*)d = *(uint4*)o;
  *(uint4*)(d + 8) = *(uint4*)(o + 8);
}

// ---------------- mega prep/convert/klalpha kernel (grid-stride, 1528 blocks) ----------------
#define P0 64     // [0,P0)      prep items 133856
#define P1 128    // [P0,P1)     alphas chunks8 102400
#define P2 288    // [P1,P2)     rho   chunks16 20096*20
#define P3 416    // [P2,P3)     nb    chunks16 256*1250
#define P4 864    // [P3,P4)     W1    chunks16 896*1250
#define P5 1120   // [P4,P5)     rnn   chunks16 512*1250
#define P6 1248   // [P5,P6)     emw   chunks16 256*1250
#define P7 1256   // [P6,P7)     wih   chunks16 896*14
#define P8 1272   // [P7,P8)     W2    chunks16 896*50
#define P9 1528   // [P8,P9)     klalpha 750000
__global__ __launch_bounds__(256) void k_mega(
    const float* __restrict__ whh,
    const float* __restrict__ muEW, const float* __restrict__ lsEW,
    const float* __restrict__ bih, const float* __restrict__ bhh,
    const float* __restrict__ wih, const float* __restrict__ emapB,
    const float* __restrict__ W1, const int* __restrict__ times,
    const float* __restrict__ muq, const float* __restrict__ lsq,
    const float* __restrict__ rho, const float* __restrict__ nb,
    const float* __restrict__ rnn, const float* __restrict__ emapW,
    const float* __restrict__ W2f, float* __restrict__ W)
{
  int b = blockIdx.x, tid = threadIdx.x;
  __shared__ float red[256];
  if (b < P0){
    u32* whhH = (u32*)(W + OFF_WHH_H);
    u32* etaWH = (u32*)(W + OFF_ETAWH);
    for (int idx = b*256 + tid; idx < 133856; idx += P0*256){
      if (idx < 80000){
        int j = idx/100; int i = idx - j*100;
        whhH[idx] = packh2(whh[j*200 + 2*i], whh[j*200 + 2*i + 1]);
      } else if (idx < 92800){
        int d = idx - 80000; int q = d >> 7; int i = d & 127;
        u32 v = 0u;
        if (i < 125){
          const float* src = (q < 50) ? (muEW + q*250) : (lsEW + (q-50)*250);
          v = packh2(src[2*i], src[2*i+1]);
        }
        etaWH[d] = v;
      } else if (idx < 93600){
        int j = idx - 92800;
        float acc = bih[j] + bhh[j];
        const float* wr = wih + (size_t)j*200;
        #pragma unroll 4
        for (int k = 0; k < 200; k++) acc += emapB[k]*wr[k];
        W[OFF_BIAS2 + j] = acc;
      } else if (idx < 133600){
        int d = idx - 93600; int j = d/50; int k = d - j*50;
        W[OFF_W1E + d] = W1[(size_t)j*20050 + 20000 + k];
      } else {
        int bb = idx - 133600; int t = times[bb];
        int* docCnt = (int*)(W + OFF_DOCCNT);
        int* docList = (int*)(W + OFF_DOCLIST);
        int pos = atomicAdd(&docCnt[t], 1);
        docList[t*256 + pos] = bb;
      }
    }
  } else if (b < P1){
    // alphas permute+pad: dst[t*50+k][r] = muq[k][t][r]; [2560][320] bf16, chunks of 8
    ushort_t* dst = (ushort_t*)(W + OFF_ALPHAB);
    for (int idx = (b-P0)*256 + tid; idx < 102400; idx += (P1-P0)*256){
      int row = idx / 40, c = (idx - row*40) << 3;
      ushort_t out[8];
      const float* src = nullptr;
      if (row < 2500){ int t = row/50, k = row - t*50; src = muq + (size_t)k*15000 + t*300; }
      #pragma unroll
      for (int j = 0; j < 8; j++){
        int r = c + j;
        float v = (src && r < 300) ? src[r] : 0.f;
        out[j] = f2bf(v);
      }
      *(uint4*)(dst + (size_t)row*320 + c) = *(uint4*)out;
    }
  } else if (b < P2){
    ushort_t* dst = (ushort_t*)(W + OFF_RHOB);
    #pragma unroll 2
    for (int i = (b-P1)*256 + tid; i < 20096*20; i += (P2-P1)*256)
      conv_row16<300, 20000, 300, 20>(rho, dst, i);
  } else if (b < P3){
    ushort_t* dst = (ushort_t*)(W + OFF_NBB);
    #pragma unroll 2
    for (int i = (b-P2)*256 + tid; i < 256*1250; i += (P3-P2)*256)
      conv_row16<20000, 256, 20000, 1250>(nb, dst, i);
  } else if (b < P4){
    ushort_t* dst = (ushort_t*)(W + OFF_W1B);
    #pragma unroll 2
    for (int i = (b-P3)*256 + tid; i < 896*1250; i += (P4-P3)*256)
      conv_row16<20050, 800, 20000, 1250>(W1, dst, i);
  } else if (b < P5){
    ushort_t* dst = (ushort_t*)(W + OFF_RNNB);
    #pragma unroll 2
    for (int i = (b-P4)*256 + tid; i < 512*1250; i += (P5-P4)*256)
      conv_row16<20000, 500, 20000, 1250>(rnn, dst, i);
  } else if (b < P6){
    ushort_t* dst = (ushort_t*)(W + OFF_EMWB);
    #pragma unroll 2
    for (int i = (b-P5)*256 + tid; i < 256*1250; i += (P6-P5)*256)
      conv_row16<20000, 200, 20000, 1250>(emapW, dst, i);
  } else if (b < P7){
    ushort_t* dst = (ushort_t*)(W + OFF_WIHB);
    #pragma unroll 2
    for (int i = (b-P6)*256 + tid; i < 896*14; i += (P7-P6)*256)
      conv_row16<200, 800, 200, 14>(wih, dst, i);
  } else if (b < P8){
    ushort_t* dst = (ushort_t*)(W + OFF_W2B);
    #pragma unroll 2
    for (int i = (b-P7)*256 + tid; i < 896*50; i += (P8-P7)*256)
      conv_row16<800, 800, 800, 50>(W2f, dst, i);
  } else {
    // kl_alpha
    const float inv_dl = 1.f/(0.005f + 1e-6f);
    const float logdl = -5.2983173665480363f;
    float local = 0.f;
    for (int idx = (b-P8)*256 + tid; idx < 750000; idx += (P9-P8)*256){
      int rem = idx % 15000; int t = rem / 300;
      float ls = lsq[idx]; float mu = muq[idx];
      if (t == 0){
        local += 0.5f*((__expf(ls) + mu*mu)/(1.f + 1e-6f) - 1.f - ls);
      } else {
        float d = mu - muq[idx - 300];
        local += 0.5f*((__expf(ls) + d*d)*inv_dl - 1.f + logdl - ls);
      }
    }
    blockReduceAdd(local, red, W + OFF_SCAL + 1);
  }
}

// ---------------- small fp32 -> bf16 convert (for mapped, after its GEMM) ----------------
__device__ inline void conv_seg(const float* __restrict__ src, int ldsrc,
                                int Mreal, int Kused,
                                ushort_t* __restrict__ dst, int Kp, int idx)
{
  int kb = Kp >> 3;
  int row = idx / kb, c = (idx - row*kb) << 3;
  ushort_t out[8];
  #pragma unroll
  for (int j = 0; j < 8; j++){
    float v = 0.f;
    int k = c + j;
    if (row < Mreal && k < Kused) v = src[(size_t)row*ldsrc + k];
    out[j] = f2bf(v);
  }
  *(uint4*)(dst + (size_t)row*Kp + c) = *(uint4*)out;
}

__global__ __launch_bounds__(256) void k_conv(const float* __restrict__ src, int ldsrc,
                                              int Mreal, int Kused,
                                              ushort_t* __restrict__ dst, int Mp, int Kp)
{
  int idx = blockIdx.x*256 + threadIdx.x;
  int kb = Kp >> 3;
  if (idx >= Mp*kb) return;
  conv_seg(src, ldsrc, Mreal, Kused, dst, Kp, idx);
}

// ---------------- shared GEMM body (MODE 0: atomic f32), 128x128 tile, split-K ------------
__device__ __forceinline__ void gemm0_body(
    const ushort_t* __restrict__ A, int lda,
    const ushort_t* __restrict__ B, int ldb,
    float* __restrict__ C, int ldc,
    int M, int N, int mT, int kS, int chunks, int bid, int tid,
    ushort_t (*As)[128*32], ushort_t (*Bs)[128*32])
{
  int kIdx = bid % kS; int rest = bid / kS;
  int mIdx = rest % mT; int nIdx = rest / mT;
  int w = tid >> 6, l = tid & 63;
  int c0 = (int)(((long long)chunks * kIdx) / kS);
  int c1 = (int)(((long long)chunks * (kIdx+1)) / kS);
  int r0 = w*32;
  const ushort_t* ga0 = A + (size_t)(mIdx*128 + r0      + (l>>2))*lda + (l&3)*8;
  const ushort_t* ga1 = A + (size_t)(mIdx*128 + r0 + 16 + (l>>2))*lda + (l&3)*8;
  const ushort_t* gb0 = B + (size_t)(nIdx*128 + r0      + (l>>2))*ldb + (l&3)*8;
  const ushort_t* gb1 = B + (size_t)(nIdx*128 + r0 + 16 + (l>>2))*ldb + (l&3)*8;
  int wr = (w >> 1)*64, wc = (w & 1)*64;
  int lr = l & 15, lq = l >> 4;
  f32x4 acc[4][4];
  #pragma unroll
  for (int i = 0; i < 4; i++)
    #pragma unroll
    for (int j = 0; j < 4; j++)
      acc[i][j] = (f32x4)0.f;

  {
    size_t ko = (size_t)c0 * 32;
    gl2lds16(ga0 + ko, As[0] + r0*32);
    gl2lds16(ga1 + ko, As[0] + r0*32 + 512);
    gl2lds16(gb0 + ko, Bs[0] + r0*32);
    gl2lds16(gb1 + ko, Bs[0] + r0*32 + 512);
  }
  asm volatile("s_waitcnt vmcnt(0)" ::: "memory");
  __builtin_amdgcn_s_barrier();

  int cur = 0;
  for (int c = c0; c < c1; c++){
    if (c + 1 < c1){
      size_t ko = (size_t)(c + 1) * 32;
      int nxt = cur ^ 1;
      gl2lds16(ga0 + ko, As[nxt] + r0*32);
      gl2lds16(ga1 + ko, As[nxt] + r0*32 + 512);
      gl2lds16(gb0 + ko, Bs[nxt] + r0*32);
      gl2lds16(gb1 + ko, Bs[nxt] + r0*32 + 512);
    }
    bf16x8 av[4], bv[4];
    #pragma unroll
    for (int i = 0; i < 4; i++)
      av[i] = *(const bf16x8*)(As[cur] + (wr + i*16 + lr)*32 + lq*8);
    #pragma unroll
    for (int j = 0; j < 4; j++)
      bv[j] = *(const bf16x8*)(Bs[cur] + (wc + j*16 + lr)*32 + lq*8);
    #pragma unroll
    for (int i = 0; i < 4; i++)
      #pragma unroll
      for (int j = 0; j < 4; j++)
        acc[i][j] = __builtin_amdgcn_mfma_f32_16x16x32_bf16(av[i], bv[j], acc[i][j], 0, 0, 0);
    asm volatile("s_waitcnt vmcnt(0)" ::: "memory");
    __builtin_amdgcn_s_barrier();
    cur ^= 1;
  }
  #pragma unroll
  for (int i = 0; i < 4; i++){
    #pragma unroll
    for (int r = 0; r < 4; r++){
      int row = mIdx*128 + wr + i*16 + lq*4 + r;
      if (row >= M) continue;
      #pragma unroll
      for (int j = 0; j < 4; j++){
        int col = nIdx*128 + wc + j*16 + lr;
        if (col >= N) continue;
        atomicAdd(&C[(size_t)row*ldc + col], acc[i][j][r]);
      }
    }
  }
}

// ---------------- fused mapped-GEMM (blocks 0..255) || hpre-GEMM (blocks 256..535) ---------
// Both independent (only depend on k_mega conversions); sum->max serialization win.
__global__ __launch_bounds__(256) void k_gemm2(
    const ushort_t* __restrict__ rnnB, const ushort_t* __restrict__ emwB, float* __restrict__ mapped,
    const ushort_t* __restrict__ nbB, const ushort_t* __restrict__ w1B, float* __restrict__ hpre)
{
  __shared__ __align__(16) ushort_t As[2][128*32];
  __shared__ __align__(16) ushort_t Bs[2][128*32];
  int bid = blockIdx.x, tid = threadIdx.x;
  if (bid < 256){
    // mapped = rnn @ eta_map_W^T  M=500 N=200 K=20000  mT=4 kS=32
    gemm0_body(rnnB, 20000, emwB, 20000, mapped, 200, 500, 200, 4, 32, 625, bid, tid, As, Bs);
  } else {
    // hpre = nb @ W1[:, :V]^T  M=256 N=800 K=20000  mT=2 kS=20
    gemm0_body(nbB, 20000, w1B, 20000, hpre, 800, 256, 800, 2, 20, 625, bid - 256, tid, As, Bs);
  }
}

// ---------------- bf16 MFMA NT GEMM: C[M,N] = A[M,K] . B[N,K]^T ----------------
// MODE 0: atomic f32; MODE 2: f32 store + col-bias.
template<int MODE>
__global__ __launch_bounds__(256) void mfma_nt(
    const ushort_t* __restrict__ A, int lda,
    const ushort_t* __restrict__ B, int ldb,
    float* __restrict__ C, _Float16* __restrict__ Ch, int ldc,
    const float* __restrict__ nBias,
    int M, int N, int mT, int kS, int chunks)
{
  __shared__ __align__(16) ushort_t As[2][128*32];
  __shared__ __align__(16) ushort_t Bs[2][128*32];
  int bid = blockIdx.x;
  int kIdx = bid % kS; int rest = bid / kS;
  int mIdx = rest % mT; int nIdx = rest / mT;
  int tid = threadIdx.x;
  int w = tid >> 6, l = tid & 63;
  int c0 = (int)(((long long)chunks * kIdx) / kS);
  int c1 = (int)(((long long)chunks * (kIdx+1)) / kS);
  int r0 = w*32;
  const ushort_t* ga0 = A + (size_t)(mIdx*128 + r0      + (l>>2))*lda + (l&3)*8;
  const ushort_t* ga1 = A + (size_t)(mIdx*128 + r0 + 16 + (l>>2))*lda + (l&3)*8;
  const ushort_t* gb0 = B + (size_t)(nIdx*128 + r0      + (l>>2))*ldb + (l&3)*8;
  const ushort_t* gb1 = B + (size_t)(nIdx*128 + r0 + 16 + (l>>2))*ldb + (l&3)*8;
  int wr = (w >> 1)*64, wc = (w & 1)*64;
  int lr = l & 15, lq = l >> 4;
  f32x4 acc[4][4];
  #pragma unroll
  for (int i = 0; i < 4; i++)
    #pragma unroll
    for (int j = 0; j < 4; j++)
      acc[i][j] = (f32x4)0.f;

  {
    size_t ko = (size_t)c0 * 32;
    gl2lds16(ga0 + ko, As[0] + r0*32);
    gl2lds16(ga1 + ko, As[0] + r0*32 + 512);
    gl2lds16(gb0 + ko, Bs[0] + r0*32);
    gl2lds16(gb1 + ko, Bs[0] + r0*32 + 512);
  }
  asm volatile("s_waitcnt vmcnt(0)" ::: "memory");
  __builtin_amdgcn_s_barrier();

  int cur = 0;
  for (int c = c0; c < c1; c++){
    if (c + 1 < c1){
      size_t ko = (size_t)(c + 1) * 32;
      int nxt = cur ^ 1;
      gl2lds16(ga0 + ko, As[nxt] + r0*32);
      gl2lds16(ga1 + ko, As[nxt] + r0*32 + 512);
      gl2lds16(gb0 + ko, Bs[nxt] + r0*32);
      gl2lds16(gb1 + ko, Bs[nxt] + r0*32 + 512);
    }
    bf16x8 av[4], bv[4];
    #pragma unroll
    for (int i = 0; i < 4; i++)
      av[i] = *(const bf16x8*)(As[cur] + (wr + i*16 + lr)*32 + lq*8);
    #pragma unroll
    for (int j = 0; j < 4; j++)
      bv[j] = *(const bf16x8*)(Bs[cur] + (wc + j*16 + lr)*32 + lq*8);
    #pragma unroll
    for (int i = 0; i < 4; i++)
      #pragma unroll
      for (int j = 0; j < 4; j++)
        acc[i][j] = __builtin_amdgcn_mfma_f32_16x16x32_bf16(av[i], bv[j], acc[i][j], 0, 0, 0);
    asm volatile("s_waitcnt vmcnt(0)" ::: "memory");
    __builtin_amdgcn_s_barrier();
    cur ^= 1;
  }
  #pragma unroll
  for (int i = 0; i < 4; i++){
    #pragma unroll
    for (int r = 0; r < 4; r++){
      int row = mIdx*128 + wr + i*16 + lq*4 + r;
      if (row >= M) continue;
      #pragma unroll
      for (int j = 0; j < 4; j++){
        int col = nIdx*128 + wc + j*16 + lr;
        if (col >= N) continue;
        float v = acc[i][j][r];
        if (MODE == 0)      atomicAdd(&C[(size_t)row*ldc + col], v);
        else                C[(size_t)row*ldc + col] = v + nBias[col];
      }
    }
  }
}

// ---------------- FUSED: LSTM+eta (blocks 0..9) || E-GEMM exp(alpha.rho^T) (blocks 10..799) ----
// LSTM part verbatim (512 threads). E part: ONE 256x256 tile per 512-thread block (8 waves,
// each owns a 128x64 quadrant). __launch_bounds__(512, 2): VGPR cap 256.
__global__ __launch_bounds__(512, 2) void k_fused_lstm_E(
    const float* __restrict__ xw, const u32* __restrict__ whhH, const uint4* __restrict__ etaW4,
    const float* __restrict__ muEB, const float* __restrict__ lsEB,
    float* __restrict__ etas, float* __restrict__ W,
    const ushort_t* __restrict__ A, const ushort_t* __restrict__ B,
    _Float16* __restrict__ Ch)
{
  __shared__ __align__(16) ushort_t As[2][256*32];  // [dbuf] 16KB each
  __shared__ __align__(16) ushort_t Bs[2][256*32];
  __shared__ uint4 hp4[2][32];
  __shared__ float zbuf[800];
  __shared__ float red[512];

  if (blockIdx.x < NSRC){
    // ================= LSTM + eta recurrence =================
    int s = blockIdx.x; int tid = threadIdx.x;
    uint4 z4; z4.x = z4.y = z4.z = z4.w = 0u;
#define DECLW(i) uint4 wa##i = z4, wb##i = z4;
    REP25(DECLW)
#undef DECLW
    float ebias = 0.f;
    if (tid < 400){
      const uint4* ra = (const uint4*)(whhH + tid*100);
      const uint4* rb = (const uint4*)(whhH + (tid + 400)*100);
#define LDW(i) wa##i = ra[i]; wb##i = rb[i];
      REP25(LDW)
#undef LDW
    } else if (tid < 500){
      int q = tid - 400;
      const uint4* re = etaW4 + q*32;
#define LDA(i) wa##i = re[i];
      REP25(LDA)
#undef LDA
#define LDB(i) wb##i = re[25+i];
      REP7(LDB)
#undef LDB
      ebias = (q < 50) ? muEB[q] : lsEB[q - 50];
    }
    float creg = 0.f, muPrev = 0.f, klLocal = 0.f;
    if (tid < 64) ((uint4*)hp4)[tid] = z4;
    __syncthreads();
    const float inv_dl = 1.f/(0.005f + 1e-6f);
    const float logdl = -5.2983173665480363f;

    for (int t = 0; t < NT_T; t++){
      const uint4* hc = hp4[t & 1];
      uint4* hn = hp4[(t + 1) & 1];
      if (tid < 400){
        float a0=0.f,a1=0.f,a2=0.f,a3=0.f,b0=0.f,b1=0.f,b2=0.f,b3=0.f;
#define DOT(i) { uint4 h = hc[i]; \
        a0 = dot2u(wa##i.x, h.x, a0); a1 = dot2u(wa##i.y, h.y, a1); \
        a2 = dot2u(wa##i.z, h.z, a2); a3 = dot2u(wa##i.w, h.w, a3); \
        b0 = dot2u(wb##i.x, h.x, b0); b1 = dot2u(wb##i.y, h.y, b1); \
        b2 = dot2u(wb##i.z, h.z, b2); b3 = dot2u(wb##i.w, h.w, b3); }
        REP25(DOT)
#undef DOT
        const float* xr = xw + (size_t)(s*50 + t)*800;
        zbuf[tid]       = ((a0+a1)+(a2+a3)) + xr[tid];
        zbuf[tid + 400] = ((b0+b1)+(b2+b3)) + xr[tid + 400];
      }
      __syncthreads();  // B1: zbuf ready
      if (tid < 200){
        float zi = zbuf[tid], zf = zbuf[200+tid], zg = zbuf[400+tid], zo = zbuf[600+tid];
        float ig = fast_sig(zi);
        float fg = fast_sig(zf);
        float gg = fast_tanh(zg);
        float og = fast_sig(zo);
        creg = fg*creg + ig*gg;
        float hv = og*fast_tanh(creg);
        ((_Float16*)hn)[tid] = (_Float16)hv;
      }
      __syncthreads();  // B2: h_t ready
      if (tid >= 400 && tid < 500){
        float e0 = ebias, e1 = 0.f, e2 = 0.f, e3 = 0.f;
#define DOTE(i) { uint4 h = hn[i]; \
        e0 = dot2u(wa##i.x, h.x, e0); e1 = dot2u(wa##i.y, h.y, e1); \
        e2 = dot2u(wa##i.z, h.z, e2); e3 = dot2u(wa##i.w, h.w, e3); }
        REP25(DOTE)
#undef DOTE
#define DOTP(i) { uint4 h = hc[25+i]; \
        e0 = dot2u(wb##i.x, h.x, e0); e1 = dot2u(wb##i.y, h.y, e1); \
        e2 = dot2u(wb##i.z, h.z, e2); e3 = dot2u(wb##i.w, h.w, e3); }
        REP7(DOTP)
#undef DOTP
        float eacc = (e0+e1)+(e2+e3);
        int q = tid - 400;
        if (q < 50){
          float mu = eacc;
          etas[(size_t)(s*50 + t)*50 + q] = mu;
          if (t == 0) klLocal += 0.5f*mu*mu/(1.f + 1e-6f);
          else { float d = mu - muPrev; klLocal += 0.5f*d*d*inv_dl; }
          muPrev = mu;
          ((_Float16*)hn)[200 + q] = (_Float16)mu;
        } else {
          float ls = eacc;
          if (t == 0) klLocal += 0.5f*(__expf(ls)/(1.f + 1e-6f) - 1.f - ls);
          else {
            ls = fminf(fmaxf(ls, -10.f), 10.f);
            klLocal += 0.5f*(__expf(ls)*inv_dl - 1.f + logdl - ls);
          }
        }
      }
    }
    __syncthreads();
    blockReduceAdd(klLocal, red, W + OFF_SCAL + 2);
  } else {
    // ================= E-GEMM (MODE 3), one 256x256 tile per block =================
    int tid = threadIdx.x;
    int v = blockIdx.x - NSRC;                  // tile id in [0, 790)
    int mIdx = v % 10; int nIdx = v / 10;       // m-fast for B-panel L2 reuse
    const int M = 2500, N = 20000, ldc = 20000;
    int w = tid >> 6, l = tid & 63;
    int r0 = w*32;
    const ushort_t* ga0 = A + (size_t)(mIdx*256 + r0      + (l>>2))*320 + (l&3)*8;
    const ushort_t* ga1 = A + (size_t)(mIdx*256 + r0 + 16 + (l>>2))*320 + (l&3)*8;
    const ushort_t* gb0 = B + (size_t)(nIdx*256 + r0      + (l>>2))*320 + (l&3)*8;
    const ushort_t* gb1 = B + (size_t)(nIdx*256 + r0 + 16 + (l>>2))*320 + (l&3)*8;
    int wr = (w >> 2)*128, wc = (w & 3)*64;
    int lr = l & 15, lq = l >> 4;
    f32x4 acc[8][4];
    #pragma unroll
    for (int i = 0; i < 8; i++)
      #pragma unroll
      for (int j = 0; j < 4; j++)
        acc[i][j] = (f32x4)0.f;

    gl2lds16(ga0, As[0] + r0*32);
    gl2lds16(ga1, As[0] + r0*32 + 512);
    gl2lds16(gb0, Bs[0] + r0*32);
    gl2lds16(gb1, Bs[0] + r0*32 + 512);
    asm volatile("s_waitcnt vmcnt(0)" ::: "memory");
    __builtin_amdgcn_s_barrier();

    int cur = 0;
    for (int c = 0; c < 10; c++){
      if (c + 1 < 10){
        size_t ko = (size_t)(c + 1) * 32;
        int nxt = cur ^ 1;
        gl2lds16(ga0 + ko, As[nxt] + r0*32);
        gl2lds16(ga1 + ko, As[nxt] + r0*32 + 512);
        gl2lds16(gb0 + ko, Bs[nxt] + r0*32);
        gl2lds16(gb1 + ko, Bs[nxt] + r0*32 + 512);
      }
      bf16x8 bv[4];
      #pragma unroll
      for (int j = 0; j < 4; j++)
        bv[j] = *(const bf16x8*)(Bs[cur] + (wc + j*16 + lr)*32 + lq*8);
      #pragma unroll
      for (int i = 0; i < 8; i++){
        bf16x8 av = *(const bf16x8*)(As[cur] + (wr + i*16 + lr)*32 + lq*8);
        #pragma unroll
        for (int j = 0; j < 4; j++)
          acc[i][j] = __builtin_amdgcn_mfma_f32_16x16x32_bf16(av, bv[j], acc[i][j], 0, 0, 0);
      }
      asm volatile("s_waitcnt vmcnt(0)" ::: "memory");
      __builtin_amdgcn_s_barrier();
      cur ^= 1;
    }
    float* Z = W + OFF_Z;
    #pragma unroll
    for (int i = 0; i < 8; i++){
      #pragma unroll
      for (int r = 0; r < 4; r++){
        int row = mIdx*256 + wr + i*16 + lq*4 + r;
        float p = 0.f;
        if (row < M){
          #pragma unroll
          for (int j = 0; j < 4; j++){
            int col = nIdx*256 + wc + j*16 + lr;
            if (col < N){
              float e = __expf(acc[i][j][r]);
              Ch[(size_t)row*ldc + col] = (_Float16)e;
              p += e;
            }
          }
        }
        p += __shfl_xor(p, 1, 16);
        p += __shfl_xor(p, 2, 16);
        p += __shfl_xor(p, 4, 16);
        p += __shfl_xor(p, 8, 16);
        if (lr == 0 && row < M) atomicAdd(&Z[row], p);
      }
    }
  }
}

// ---------------- h1 = relu(hpre + b1 + eta_std @ W1E^T) -> bf16 ----------------
__global__ __launch_bounds__(256) void k_h1(
    const float* __restrict__ hpre, const float* __restrict__ b1, const float* __restrict__ w1e,
    const float* __restrict__ etas, const int* __restrict__ times, const int* __restrict__ srcs,
    ushort_t* __restrict__ h1B)
{
  int b = blockIdx.x, tid = threadIdx.x;
  __shared__ float et[50];
  int tb = times[b], sb = srcs[b];
  if (tid < 50) et[tid] = etas[(size_t)(sb*50 + tb)*50 + tid];
  __syncthreads();
  for (int j = tid; j < 800; j += 256){
    float acc = hpre[(size_t)b*800 + j] + b1[j];
    const float* wrow = w1e + (size_t)j*50;
    #pragma unroll
    for (int k = 0; k < 50; k++) acc += et[k]*wrow[k];
    h1B[(size_t)b*800 + j] = f2bf(fmaxf(acc, 0.f));
  }
}

// ---------------- theta head (h2pre + b2, relu folded; wcoef = theta/Z) ----------------
__global__ __launch_bounds__(256) void k_thfin(
    const float* __restrict__ h2g, const float* __restrict__ b2, const float* __restrict__ etas,
    const int* __restrict__ times, const int* __restrict__ srcs,
    const float* __restrict__ muW, const float* __restrict__ muB,
    const float* __restrict__ lsW, const float* __restrict__ lsB,
    const float* __restrict__ clsW, const float* __restrict__ clsB,
    const float* __restrict__ Zrow, float* __restrict__ wcoef, float* __restrict__ W)
{
  int b = blockIdx.x, tid = threadIdx.x;
  __shared__ float h2s[800], mu[50], lsv[50], et[50], th[50], lg[10], red[64], shm[2];
  for (int j = tid; j < 800; j += 256) h2s[j] = fmaxf(h2g[(size_t)b*800 + j] + b2[j], 0.f);
  int tb = times[b], sb = srcs[b];
  if (tid < 50) et[tid] = etas[(size_t)(sb*50 + tb)*50 + tid];
  __syncthreads();
  if (tid < 100){
    int q = (tid < 50) ? tid : tid - 50;
    const float* w = (tid < 50) ? (muW + (size_t)q*800) : (lsW + (size_t)q*800);
    float acc = (tid < 50) ? muB[q] : lsB[q];
    #pragma unroll 8
    for (int j = 0; j < 800; j++) acc += h2s[j]*w[j];
    if (tid < 50) mu[q] = acc;
    else lsv[q] = fminf(fmaxf(acc, -10.f), 10.f);
  }
  __syncthreads();
  if (tid == 0){ float m = -1e30f; for (int k = 0; k < 50; k++) m = fmaxf(m, mu[k]); shm[0] = m; }
  __syncthreads();
  if (tid < 50) th[tid] = __expf(mu[tid] - shm[0]);
  __syncthreads();
  if (tid == 0){ float z = 0.f; for (int k = 0; k < 50; k++) z += th[k]; shm[1] = z; }
  __syncthreads();
  if (tid < 64) red[tid] = 0.f;
  if (tid < 50){
    float t_ = th[tid]/shm[1]; th[tid] = t_;
    wcoef[(size_t)b*50 + tid] = t_/Zrow[tb*50 + tid];
    float d = mu[tid] - et[tid];
    red[tid] = 0.5f*((__expf(lsv[tid]) + d*d)/(1.f + 1e-6f) - 1.f - lsv[tid]);
  }
  __syncthreads();
  if (tid < 10){
    float a = clsB[tid];
    #pragma unroll
    for (int k = 0; k < 50; k++) a += th[k]*clsW[tid*50 + k];
    lg[tid] = a;
  }
  __syncthreads();
  if (tid == 0){
    float m = -1e30f; for (int i = 0; i < 10; i++) m = fmaxf(m, lg[i]);
    float z = 0.f; for (int i = 0; i < 10; i++) z += __expf(lg[i] - m);
    float lse = m + __logf(z);
    atomicAdd(W + OFF_SCAL + 4, lse - lg[sb]);
    float ssum = 0.f; for (int i = 0; i < 50; i++) ssum += red[i];
    atomicAdd(W + OFF_SCAL + 3, ssum);
  }
}

// ---------------- nll: E already exponentiated ----------------
__global__ __launch_bounds__(256) void k_nll(
    const _Float16* __restrict__ E, const float* __restrict__ wcoef,
    const float* __restrict__ bows, float* __restrict__ W)
{
  int t = blockIdx.x/10, vc = blockIdx.x%10;
  int v0 = vc*2000;
  int tid = threadIdx.x;
  const int* docCnt = (const int*)(W + OFF_DOCCNT);
  const int* docList = (const int*)(W + OFF_DOCLIST);
  __shared__ float wch[64*50];
  __shared__ int ids[64];
  __shared__ float red[256];
  int nd = docCnt[t];
  float acc = 0.f;
  for (int d0 = 0; d0 < nd; d0 += 64){
    int ndc = min(64, nd - d0);
    __syncthreads();
    for (int i = tid; i < ndc*50; i += 256){
      int d = i/50, k = i - d*50;
      int bb = docList[t*256 + d0 + d];
      if (k == 0) ids[d] = bb;
      wch[i] = wcoef[(size_t)bb*50 + k];
    }
    __syncthreads();
    for (int v = v0 + tid; v < v0 + 2000; v += 256){
      float e[50];
      #pragma unroll
      for (int k = 0; k < 50; k++)
        e[k] = (float)E[(size_t)(t*50 + k)*NVOC + v];
      for (int d = 0; d < ndc; d++){
        float s = 0.f;
        #pragma unroll
        for (int k = 0; k < 50; k++) s += wch[d*50 + k]*e[k];
        acc += bows[(size_t)ids[d]*NVOC + v]*__logf(s);
      }
    }
  }
  __syncthreads();
  blockReduceAdd(acc, red, W + OFF_SCAL + 0);
}

// ---------------- finalize ----------------
__global__ void k_final(const float* __restrict__ W, const int* __restrict__ ndocs, float* __restrict__ out)
{
  if (blockIdx.x == 0 && threadIdx.x == 0){
    float coeff = (float)ndocs[0] / 256.f;
    const float* scal = W + OFF_SCAL;
    float nll  = -scal[0]*coeff;
    float kla  = scal[1];
    float kle  = scal[2];
    float klth = scal[3]*coeff;
    float pred = scal[4]*coeff;
    out[0] = nll + kla + kle + klth + pred;
    out[1] = nll; out[2] = kla; out[3] = kle; out[4] = klth; out[5] = pred;
  }
}

extern "C" void kernel_launch(void* const* d_in, const int* in_sizes, int n_in,
                              void* d_out, int out_size, void* d_ws, size_t ws_size,
                              hipStream_t stream)
{
  (void)in_sizes; (void)n_in; (void)out_size; (void)ws_size;
  const float* bows  = (const float*)d_in[1];
  const float* nb    = (const float*)d_in[2];
  const int*   times = (const int*)d_in[3];
  const int*   srcs  = (const int*)d_in[4];
  const float* rnn   = (const float*)d_in[5];
  const int*   ndocs = (const int*)d_in[6];
  const float* muq   = (const float*)d_in[7];
  const float* lsq   = (const float*)d_in[8];
  const float* rho   = (const float*)d_in[9];
  const float* W1    = (const float*)d_in[10];
  const float* b1    = (const float*)d_in[11];
  const float* W2    = (const float*)d_in[12];
  const float* b2    = (const float*)d_in[13];
  const float* muthW = (const float*)d_in[14];
  const float* muthB = (const float*)d_in[15];
  const float* lsthW = (const float*)d_in[16];
  const float* lsthB = (const float*)d_in[17];
  const float* emapW = (const float*)d_in[18];
  const float* emapB = (const float*)d_in[19];
  const float* wih   = (const float*)d_in[20];
  const float* whh   = (const float*)d_in[21];
  const float* bih   = (const float*)d_in[22];
  const float* bhh   = (const float*)d_in[23];
  const float* muEW  = (const float*)d_in[24];
  const float* muEB  = (const float*)d_in[25];
  const float* lsEW  = (const float*)d_in[26];
  const float* lsEB  = (const float*)d_in[27];
  const float* clsW  = (const float*)d_in[28];
  const float* clsB  = (const float*)d_in[29];

  float* W = (float*)d_ws;
  ushort_t* alphaB = (ushort_t*)(W + OFF_ALPHAB);
  ushort_t* rhoB   = (ushort_t*)(W + OFF_RHOB);
  ushort_t* nbB    = (ushort_t*)(W + OFF_NBB);
  ushort_t* w1B    = (ushort_t*)(W + OFF_W1B);
  ushort_t* rnnB   = (ushort_t*)(W + OFF_RNNB);
  ushort_t* emwB   = (ushort_t*)(W + OFF_EMWB);
  ushort_t* wihB   = (ushort_t*)(W + OFF_WIHB);
  ushort_t* w2B    = (ushort_t*)(W + OFF_W2B);
  ushort_t* mapB   = (ushort_t*)(W + OFF_MAPB);
  ushort_t* h1B    = (ushort_t*)(W + OFF_H1B);
  _Float16* Ehalf  = (_Float16*)(W + OFF_LOGITH);

  hipMemsetAsync(d_ws, 0, MEMSET_BYTES, stream);

  // one launch: prep + all bf16 conversions + kl_alpha (grid-stride, 1528 blocks)
  k_mega<<<1528, 256, 0, stream>>>(whh, muEW, lsEW, bih, bhh, wih, emapB, W1, times,
                                   muq, lsq, rho, nb, rnn, emapW, W2, W);

  // FUSED independent GEMMs: blocks 0..255 mapped (M=500 N=200 K=20000, split-K 32),
  // blocks 256..535 hpre (M=256 N=800 K=20000, split-K 20). sum->max serialization.
  k_gemm2<<<536, 256, 0, stream>>>(rnnB, emwB, W + OFF_MAPPED, nbB, w1B, W + OFF_HPRE);

  // mapped -> bf16 [512][224]
  k_conv<<<56, 256, 0, stream>>>(W + OFF_MAPPED, 200, 500, 200, mapB, 512, 224);

  // xw = mapped @ wih^T + bias2  M=500 N=800 K=224
  mfma_nt<2><<<4*7, 256, 0, stream>>>(
      mapB, 224, wihB, 224, W + OFF_XW, nullptr, 800, W + OFF_BIAS2,
      500, 800, 4, 1, 7);

  // FUSED: blocks 0..9 LSTM (reads xw), blocks 10..799 E-GEMM 256x256/block (overwrites
  // union region; safe: mapped & hpre GEMMs already consumed rnnB/emwB/w1B)
  k_fused_lstm_E<<<NSRC + 790, 512, 0, stream>>>(
      W + OFF_XW, (const u32*)(W + OFF_WHH_H), (const uint4*)(W + OFF_ETAWH),
      muEB, lsEB, W + OFF_ETAS, W, alphaB, rhoB, Ehalf);

  k_h1<<<256, 256, 0, stream>>>(W + OFF_HPRE, b1, W + OFF_W1E, W + OFF_ETAS, times, srcs, h1B);

  // h2pre = h1 @ W2^T  M=256 N=800 K=800  (split-K atomic; b2+relu folded into k_thfin)
  mfma_nt<0><<<2*7*2, 256, 0, stream>>>(
      h1B, 800, w2B, 800, W + OFF_H2, nullptr, 800, nullptr,
      256, 800, 2, 2, 25);

  k_thfin<<<256, 256, 0, stream>>>(W + OFF_H2, b2, W + OFF_ETAS, times, srcs,
                                   muthW, muthB, lsthW, lsthB, clsW, clsB,
                                   W + OFF_Z, W + OFF_WCOEF, W);

  k_nll<<<500, 256, 0, stream>>>(Ehalf, W + OFF_WCOEF, bows, W);

  k_final<<<1, 64, 0, stream>>>(W, ndocs, (float*)d_out);
}